// Round 1
// baseline (570.649 us; speedup 1.0000x reference)
//
#include <hip/hip_runtime.h>
#include <cstdint>

typedef unsigned short u16;
typedef __attribute__((ext_vector_type(8))) short s16x8;   // 8 bf16 (4 VGPR) MFMA A/B frag
typedef __attribute__((ext_vector_type(4))) unsigned short u16x4;
typedef __attribute__((ext_vector_type(4))) float f32x4;   // MFMA C/D frag

// ---------- helpers ----------
__device__ __forceinline__ u16 f2bf(float f) {
  union { float f; uint32_t u; } c; c.f = f;
  uint32_t r = c.u + 0x7FFFu + ((c.u >> 16) & 1u);   // RNE
  return (u16)(r >> 16);
}
__device__ __forceinline__ float wave_sum_f(float v) {
#pragma unroll
  for (int o = 32; o > 0; o >>= 1) v += __shfl_xor(v, o);
  return v;
}
__device__ __forceinline__ float wave_max_f(float v) {
#pragma unroll
  for (int o = 32; o > 0; o >>= 1) v = fmaxf(v, __shfl_xor(v, o));
  return v;
}
__device__ __forceinline__ int wave_sum_i(int v) {
#pragma unroll
  for (int o = 32; o > 0; o >>= 1) v += __shfl_xor(v, o);
  return v;
}

// ---------- elementwise cast fp32 -> bf16 ----------
__global__ __launch_bounds__(256)
void cast_f32_bf16(const float* __restrict__ in, u16* __restrict__ out) {
  long i = ((long)blockIdx.x * 256 + threadIdx.x) * 4;
  f32x4 v = *(const f32x4*)(in + i);
  u16x4 o;
#pragma unroll
  for (int j = 0; j < 4; ++j) o[j] = f2bf(v[j]);
  *(u16x4*)(out + i) = o;
}

// ---------- cast+transpose fp32 [R][C] -> bf16 [C][R] ----------
__global__ __launch_bounds__(256)
void transpose_cast_f32_bf16(const float* __restrict__ in, u16* __restrict__ out,
                             int R, int C) {
  __shared__ float tile[32][33];
  int r0 = blockIdx.y * 32, c0 = blockIdx.x * 32;
  int tid = threadIdx.x;
  int tr = tid >> 3, tc4 = (tid & 7) * 4;
  f32x4 v = *(const f32x4*)(in + (long)(r0 + tr) * C + c0 + tc4);
#pragma unroll
  for (int j = 0; j < 4; ++j) tile[tr][tc4 + j] = v[j];
  __syncthreads();
  u16x4 o;
#pragma unroll
  for (int j = 0; j < 4; ++j) o[j] = f2bf(tile[tc4 + j][tr]);
  *(u16x4*)(out + (long)(c0 + tr) * R + r0 + tc4) = o;
}

// ---------- transpose bf16 [z][R][C] -> [z][C][R] ----------
__global__ __launch_bounds__(256)
void transpose_bf16(const u16* __restrict__ in, u16* __restrict__ out,
                    int R, int C) {
  __shared__ u16 tile[32][36];
  long zin = (long)blockIdx.z * R * C;
  int r0 = blockIdx.y * 32, c0 = blockIdx.x * 32;
  int tid = threadIdx.x;
  int tr = tid >> 3, tc4 = (tid & 7) * 4;
  u16x4 v = *(const u16x4*)(in + zin + (long)(r0 + tr) * C + c0 + tc4);
#pragma unroll
  for (int j = 0; j < 4; ++j) tile[tr][tc4 + j] = v[j];
  __syncthreads();
  u16x4 o;
#pragma unroll
  for (int j = 0; j < 4; ++j) o[j] = tile[tc4 + j][tr];
  *(u16x4*)(out + zin + (long)(c0 + tr) * R + r0 + tc4) = o;
}

// ---------- generic MFMA GEMM: C[M][N] = A[M][K] @ Bt[N][K]^T, batched via z ----------
#define BM 128
#define BN 128
#define BKK 32
#define LDSP 40   // padded LDS row (bf16 elems): 80 B stride -> ~2-way banks (free)

enum { EPI_BF16_BIAS = 0, EPI_F32_SCALE = 1, EPI_F32 = 2,
       EPI_RELU_BF16_BIAS = 3, EPI_F32_BIAS_RESID = 4 };

template <int EPI>
__global__ __launch_bounds__(256, 2)
void gemm_bt(const u16* __restrict__ A, const u16* __restrict__ Bt,
             const float* __restrict__ bias, const float* __restrict__ resid,
             void* __restrict__ Cout, int M, int N, int K,
             long long batchA, long long batchB, long long batchC, float scale) {
  __shared__ u16 As[BM * LDSP];
  __shared__ u16 Bs[BN * LDSP];
  const int b = blockIdx.z;
  const u16* Ab = A + (long)b * batchA;
  const u16* Bb = Bt + (long)b * batchB;
  const int row0 = blockIdx.y * BM;
  const int col0 = blockIdx.x * BN;
  const int tid = threadIdx.x;
  const int lane = tid & 63, wid = tid >> 6;
  const int wr = wid >> 1, wc = wid & 1;             // 2x2 wave grid, 64x64 each
  const int l15 = lane & 15, lk = (lane >> 4) * 8;   // frag: row=lane&15, k=(lane>>4)*8+j

  f32x4 acc[4][4] = {};

  for (int k0 = 0; k0 < K; k0 += BKK) {
#pragma unroll
    for (int i = 0; i < 2; ++i) {           // stage 128x32 A and B tiles, 16B/lane
      int c = i * 256 + tid;
      int r = c >> 2;
      int cg = (c & 3) * 8;
      *(s16x8*)(&As[r * LDSP + cg]) = *(const s16x8*)(Ab + (long)(row0 + r) * K + k0 + cg);
      *(s16x8*)(&Bs[r * LDSP + cg]) = *(const s16x8*)(Bb + (long)(col0 + r) * K + k0 + cg);
    }
    __syncthreads();
    s16x8 af[4], bfv[4];
#pragma unroll
    for (int m = 0; m < 4; ++m)
      af[m] = *(const s16x8*)(&As[(wr * 64 + m * 16 + l15) * LDSP + lk]);
#pragma unroll
    for (int n = 0; n < 4; ++n)
      bfv[n] = *(const s16x8*)(&Bs[(wc * 64 + n * 16 + l15) * LDSP + lk]);
#pragma unroll
    for (int m = 0; m < 4; ++m)
#pragma unroll
      for (int n = 0; n < 4; ++n)
        acc[m][n] = __builtin_amdgcn_mfma_f32_16x16x32_bf16(af[m], bfv[n], acc[m][n], 0, 0, 0);
    __syncthreads();
  }

  // epilogue: C/D layout col=lane&15, row=(lane>>4)*4+reg  [measured m89/m91]
  const long cb = (long)b * batchC;
#pragma unroll
  for (int m = 0; m < 4; ++m) {
    int rbase = row0 + wr * 64 + m * 16 + (lane >> 4) * 4;
#pragma unroll
    for (int n = 0; n < 4; ++n) {
      int col = col0 + wc * 64 + n * 16 + l15;
#pragma unroll
      for (int r = 0; r < 4; ++r) {
        long idx = cb + (long)(rbase + r) * N + col;
        float v = acc[m][n][r];
        if (EPI == EPI_BF16_BIAS) {
          ((u16*)Cout)[idx] = f2bf(v + bias[col]);
        } else if (EPI == EPI_F32_SCALE) {
          ((float*)Cout)[idx] = v * scale;
        } else if (EPI == EPI_F32) {
          ((float*)Cout)[idx] = v;
        } else if (EPI == EPI_RELU_BF16_BIAS) {
          ((u16*)Cout)[idx] = f2bf(fmaxf(v + bias[col], 0.0f));
        } else { // EPI_F32_BIAS_RESID
          ((float*)Cout)[idx] = v + bias[col] + resid[idx];
        }
      }
    }
  }
}

// ---------- per-row top-k threshold (radix select) + sparse softmax ----------
// Reference: sparse = where(score >= kth_largest, score, 0); softmax over ALL
// entries (dropped ones contribute exp(0 - m)). One block per row, S=2048.
__global__ __launch_bounds__(256)
void topk_softmax(const float* __restrict__ scores, u16* __restrict__ P, int topk) {
  const long rowoff = (long)blockIdx.x * 2048;
  const int tid = threadIdx.x, lane = tid & 63, wid = tid >> 6;
  __shared__ float sred[4];
  __shared__ int ired[4];

  float v[8]; uint32_t kv[8];
#pragma unroll
  for (int j = 0; j < 8; ++j) {
    float f = scores[rowoff + j * 256 + tid];
    v[j] = f;
    union { float f; uint32_t u; } c; c.f = f;
    kv[j] = (c.u & 0x80000000u) ? ~c.u : (c.u | 0x80000000u);  // monotonic key
  }
  // row max
  float m = v[0];
#pragma unroll
  for (int j = 1; j < 8; ++j) m = fmaxf(m, v[j]);
  m = wave_max_f(m);
  if (lane == 0) sred[wid] = m;
  __syncthreads();
  m = fmaxf(fmaxf(sred[0], sred[1]), fmaxf(sred[2], sred[3]));
  __syncthreads();

  // bitwise radix select: cur -> topk-th largest key
  uint32_t cur = 0;
  for (int bit = 31; bit >= 0; --bit) {
    uint32_t cand = cur | (1u << bit);
    int c = 0;
#pragma unroll
    for (int j = 0; j < 8; ++j) c += (kv[j] >= cand);
    c = wave_sum_i(c);
    if (lane == 0) ired[wid] = c;
    __syncthreads();
    int tot = ired[0] + ired[1] + ired[2] + ired[3];
    __syncthreads();
    if (tot >= topk) cur = cand;
  }

  // sparse softmax: dropped -> 0.0; row max of sparse row = max(m, 0)
  float mm = fmaxf(m, 0.0f);
  float p[8], s = 0.0f;
#pragma unroll
  for (int j = 0; j < 8; ++j) {
    float val = (kv[j] >= cur) ? v[j] : 0.0f;
    p[j] = __expf(val - mm);
    s += p[j];
  }
  s = wave_sum_f(s);
  if (lane == 0) sred[wid] = s;
  __syncthreads();
  float inv = 1.0f / (sred[0] + sred[1] + sred[2] + sred[3]);
#pragma unroll
  for (int j = 0; j < 8; ++j) P[rowoff + j * 256 + tid] = f2bf(p[j] * inv);
}

// ---------- fused (a [+ r]) -> LayerNorm -> fp32 out [+ bf16 out] ----------
__global__ __launch_bounds__(256)
void add_ln(const float* __restrict__ a, const float* __restrict__ r,
            const float* __restrict__ gamma, const float* __restrict__ beta,
            float* __restrict__ outf, u16* __restrict__ outb) {
  const long off = (long)blockIdx.x * 1024;
  const int tid = threadIdx.x, lane = tid & 63, wid = tid >> 6;
  __shared__ float sred[4];
  float x[4];
#pragma unroll
  for (int j = 0; j < 4; ++j) {
    int col = j * 256 + tid;
    float t = a[off + col];
    if (r) t += r[off + col];
    x[j] = t;
  }
  float s = x[0] + x[1] + x[2] + x[3];
  s = wave_sum_f(s);
  if (lane == 0) sred[wid] = s;
  __syncthreads();
  float mu = (sred[0] + sred[1] + sred[2] + sred[3]) * (1.0f / 1024.0f);
  __syncthreads();
  float q = 0.0f;
#pragma unroll
  for (int j = 0; j < 4; ++j) { float d = x[j] - mu; q += d * d; }
  q = wave_sum_f(q);
  if (lane == 0) sred[wid] = q;
  __syncthreads();
  float var = (sred[0] + sred[1] + sred[2] + sred[3]) * (1.0f / 1024.0f);
  float inv = rsqrtf(var + 1e-6f);
#pragma unroll
  for (int j = 0; j < 4; ++j) {
    int col = j * 256 + tid;
    float o = (x[j] - mu) * inv * gamma[col] + beta[col];
    if (outf) outf[off + col] = o;
    if (outb) outb[off + col] = f2bf(o);
  }
}

// ---------- launch ----------
extern "C" void kernel_launch(void* const* d_in, const int* in_sizes, int n_in,
                              void* d_out, int out_size, void* d_ws, size_t ws_size,
                              hipStream_t stream) {
  const float* x   = (const float*)d_in[0];
  const float* Wq  = (const float*)d_in[1];
  const float* bq  = (const float*)d_in[2];
  const float* Wk  = (const float*)d_in[3];
  const float* bk  = (const float*)d_in[4];
  const float* Wv  = (const float*)d_in[5];
  const float* bv  = (const float*)d_in[6];
  const float* W1  = (const float*)d_in[7];
  const float* b1  = (const float*)d_in[8];
  const float* W2  = (const float*)d_in[9];
  const float* b2  = (const float*)d_in[10];
  const float* g1  = (const float*)d_in[11];
  const float* be1 = (const float*)d_in[12];
  const float* g2  = (const float*)d_in[13];
  const float* be2 = (const float*)d_in[14];

  const int Bz = 4, S = 2048, Dm = 1024, Ff = 4096;
  const int M = Bz * S; // 8192

  char* ws = (char*)d_ws;
  const size_t MBy = 1024u * 1024u;
  // slab plan (peak 198 MB), reuse after liveness ends:
  u16*  wqT    = (u16*)(ws + 0 * MBy);     // 2 MB [Dm][Dm]
  u16*  wkT    = (u16*)(ws + 2 * MBy);
  u16*  wvT    = (u16*)(ws + 4 * MBy);
  u16*  w1T    = (u16*)(ws + 6 * MBy);     // 8 MB [Ff][Dm]
  u16*  w2T    = (u16*)(ws + 14 * MBy);    // 8 MB [Dm][Ff]
  u16*  xbf    = (u16*)(ws + 22 * MBy);    // 16 MB
  u16*  qbf    = (u16*)(ws + 38 * MBy);    // 16 MB
  u16*  kbf    = (u16*)(ws + 54 * MBy);    // 16 MB
  u16*  vbf    = (u16*)(ws + 70 * MBy);    // 16 MB
  u16*  vT     = (u16*)(ws + 86 * MBy);    // 16 MB [B][Dm][S]
  float* scores= (float*)(ws + 102 * MBy); // 64 MB [B][S][S]
  u16*  P      = (u16*)(ws + 166 * MBy);   // 32 MB
  float* attn  = (float*)(ws + 102 * MBy); // 32 MB (reuse scores; dead after softmax)
  float* out1  = (float*)(ws + 134 * MBy); // 32 MB
  u16*  out1b  = (u16*)(ws + 22 * MBy);    // 16 MB (reuse xbf)
  u16*  hbf    = (u16*)(ws + 38 * MBy);    // 64 MB (reuse q/k/v/vT)
  float* y     = (float*)(ws + 166 * MBy); // 32 MB (reuse P)

  dim3 blk(256);

  // casts
  cast_f32_bf16<<<dim3((unsigned)((long)M * Dm / 1024)), blk, 0, stream>>>(x, xbf);
  transpose_cast_f32_bf16<<<dim3(Dm / 32, Dm / 32), blk, 0, stream>>>(Wq, wqT, Dm, Dm);
  transpose_cast_f32_bf16<<<dim3(Dm / 32, Dm / 32), blk, 0, stream>>>(Wk, wkT, Dm, Dm);
  transpose_cast_f32_bf16<<<dim3(Dm / 32, Dm / 32), blk, 0, stream>>>(Wv, wvT, Dm, Dm);
  transpose_cast_f32_bf16<<<dim3(Ff / 32, Dm / 32), blk, 0, stream>>>(W1, w1T, Dm, Ff);
  transpose_cast_f32_bf16<<<dim3(Dm / 32, Ff / 32), blk, 0, stream>>>(W2, w2T, Ff, Dm);

  // QKV projections: [M][Dm] = xbf @ W^T, +bias, out bf16
  gemm_bt<EPI_BF16_BIAS><<<dim3(Dm / BN, M / BM, 1), blk, 0, stream>>>(
      xbf, wqT, bq, nullptr, qbf, M, Dm, Dm, 0, 0, 0, 1.0f);
  gemm_bt<EPI_BF16_BIAS><<<dim3(Dm / BN, M / BM, 1), blk, 0, stream>>>(
      xbf, wkT, bk, nullptr, kbf, M, Dm, Dm, 0, 0, 0, 1.0f);
  gemm_bt<EPI_BF16_BIAS><<<dim3(Dm / BN, M / BM, 1), blk, 0, stream>>>(
      xbf, wvT, bv, nullptr, vbf, M, Dm, Dm, 0, 0, 0, 1.0f);

  // v -> v^T per batch for PV GEMM
  transpose_bf16<<<dim3(Dm / 32, S / 32, Bz), blk, 0, stream>>>(vbf, vT, S, Dm);

  // scores[b] = q[b] @ k[b]^T / sqrt(Dm)   (k row-major IS the Bt format)
  gemm_bt<EPI_F32_SCALE><<<dim3(S / BN, S / BM, Bz), blk, 0, stream>>>(
      qbf, kbf, nullptr, nullptr, scores, S, S, Dm,
      (long long)S * Dm, (long long)S * Dm, (long long)S * S, 0.03125f);

  // top-k threshold + sparse softmax -> P (bf16)
  topk_softmax<<<dim3(Bz * S), blk, 0, stream>>>(scores, P, (int)(0.5f * S));

  // attn_out[b] = P[b] @ v[b]
  gemm_bt<EPI_F32><<<dim3(Dm / BN, S / BM, Bz), blk, 0, stream>>>(
      P, vT, nullptr, nullptr, attn, S, Dm, S,
      (long long)S * S, (long long)Dm * S, (long long)S * Dm, 1.0f);

  // out1 = LN(x + attn_out) -> fp32 + bf16
  add_ln<<<dim3(M), blk, 0, stream>>>(x, attn, g1, be1, out1, out1b);

  // h = relu(out1 @ W1 + b1) -> bf16
  gemm_bt<EPI_RELU_BF16_BIAS><<<dim3(Ff / BN, M / BM, 1), blk, 0, stream>>>(
      out1b, w1T, b1, nullptr, hbf, M, Ff, Dm, 0, 0, 0, 1.0f);

  // y = h @ W2 + b2 + out1
  gemm_bt<EPI_F32_BIAS_RESID><<<dim3(Dm / BN, M / BM, 1), blk, 0, stream>>>(
      hbf, w2T, b2, out1, y, M, Dm, Ff, 0, 0, 0, 1.0f);

  // out = LN(y)
  add_ln<<<dim3(M), blk, 0, stream>>>(y, nullptr, g2, be2, (float*)d_out, nullptr);
}

// Round 2
// 506.089 us; speedup vs baseline: 1.1276x; 1.1276x over previous
//
#include <hip/hip_runtime.h>
#include <cstdint>

typedef unsigned short u16;
typedef __attribute__((ext_vector_type(8))) short s16x8;   // 8 bf16 (4 VGPR) MFMA A/B frag
typedef __attribute__((ext_vector_type(4))) unsigned short u16x4;
typedef __attribute__((ext_vector_type(4))) float f32x4;   // MFMA C/D frag

// ---------- helpers ----------
__device__ __forceinline__ u16 f2bf(float f) {
  union { float f; uint32_t u; } c; c.f = f;
  uint32_t r = c.u + 0x7FFFu + ((c.u >> 16) & 1u);   // RNE
  return (u16)(r >> 16);
}
__device__ __forceinline__ float wave_sum_f(float v) {
#pragma unroll
  for (int o = 32; o > 0; o >>= 1) v += __shfl_xor(v, o);
  return v;
}
__device__ __forceinline__ float wave_max_f(float v) {
#pragma unroll
  for (int o = 32; o > 0; o >>= 1) v = fmaxf(v, __shfl_xor(v, o));
  return v;
}
__device__ __forceinline__ int wave_sum_i(int v) {
#pragma unroll
  for (int o = 32; o > 0; o >>= 1) v += __shfl_xor(v, o);
  return v;
}
// async global->LDS, 16B per lane, wave-uniform LDS base (+lane*16 implicit)
__device__ __forceinline__ void gload16(const u16* g, u16* l) {
  __builtin_amdgcn_global_load_lds(
      (const __attribute__((address_space(1))) unsigned int*)g,
      (__attribute__((address_space(3))) unsigned int*)l,
      16, 0, 0);
}

// ---------- elementwise cast fp32 -> bf16 ----------
__global__ __launch_bounds__(256)
void cast_f32_bf16(const float* __restrict__ in, u16* __restrict__ out) {
  long i = ((long)blockIdx.x * 256 + threadIdx.x) * 4;
  f32x4 v = *(const f32x4*)(in + i);
  u16x4 o;
#pragma unroll
  for (int j = 0; j < 4; ++j) o[j] = f2bf(v[j]);
  *(u16x4*)(out + i) = o;
}

// ---------- cast+transpose fp32 [R][C] -> bf16 [C][R] ----------
__global__ __launch_bounds__(256)
void transpose_cast_f32_bf16(const float* __restrict__ in, u16* __restrict__ out,
                             int R, int C) {
  __shared__ float tile[32][33];
  int r0 = blockIdx.y * 32, c0 = blockIdx.x * 32;
  int tid = threadIdx.x;
  int tr = tid >> 3, tc4 = (tid & 7) * 4;
  f32x4 v = *(const f32x4*)(in + (long)(r0 + tr) * C + c0 + tc4);
#pragma unroll
  for (int j = 0; j < 4; ++j) tile[tr][tc4 + j] = v[j];
  __syncthreads();
  u16x4 o;
#pragma unroll
  for (int j = 0; j < 4; ++j) o[j] = f2bf(tile[tc4 + j][tr]);
  *(u16x4*)(out + (long)(c0 + tr) * R + r0 + tc4) = o;
}

// ---------- transpose bf16 [z][R][C] -> [z][C][R] ----------
__global__ __launch_bounds__(256)
void transpose_bf16(const u16* __restrict__ in, u16* __restrict__ out,
                    int R, int C) {
  __shared__ u16 tile[32][36];
  long zin = (long)blockIdx.z * R * C;
  int r0 = blockIdx.y * 32, c0 = blockIdx.x * 32;
  int tid = threadIdx.x;
  int tr = tid >> 3, tc4 = (tid & 7) * 4;
  u16x4 v = *(const u16x4*)(in + zin + (long)(r0 + tr) * C + c0 + tc4);
#pragma unroll
  for (int j = 0; j < 4; ++j) tile[tr][tc4 + j] = v[j];
  __syncthreads();
  u16x4 o;
#pragma unroll
  for (int j = 0; j < 4; ++j) o[j] = tile[tc4 + j][tr];
  *(u16x4*)(out + zin + (long)(c0 + tr) * R + r0 + tc4) = o;
}

// ---------- generic MFMA GEMM: C[M][N] = A[M][K] @ Bt[N][K]^T, batched ----------
// m97 structure: 128x128 tile, BK=32, global_load_lds width=16 into LINEAR LDS,
// both-sides XOR chunk swizzle (phys16Bchunk = logical ^ ((row>>1)&3)) so the
// fragment ds_read_b128 is ~2-way banked (free, m136). 1D grid with bijective
// XCD swizzle (m204).
#define BM 128
#define BN 128
#define BKK 32

enum { EPI_BF16_BIAS = 0, EPI_F32_SCALE = 1, EPI_F32 = 2,
       EPI_RELU_BF16_BIAS = 3, EPI_F32_BIAS_RESID = 4 };

template <int EPI>
__global__ __launch_bounds__(256, 2)
void gemm_bt(const u16* __restrict__ A, const u16* __restrict__ Bt,
             const float* __restrict__ bias, const float* __restrict__ resid,
             void* __restrict__ Cout, int M, int N, int K, int tx, int ty,
             long long batchA, long long batchB, long long batchC, float scale) {
  __shared__ u16 As[BM * BKK];   // 8 KB, linear (required by global_load_lds)
  __shared__ u16 Bs[BN * BKK];

  // bijective XCD swizzle (m204)
  const int nwg = gridDim.x;
  const int orig = blockIdx.x;
  const int q = nwg >> 3, r = nwg & 7;
  const int xcd = orig & 7, idx = orig >> 3;
  const int wg = (xcd < r ? xcd * (q + 1) : r * (q + 1) + (xcd - r) * q) + idx;
  const int bx = wg % tx;
  const int tmp = wg / tx;
  const int by = tmp % ty;
  const int b  = tmp / ty;

  const u16* Ab = A + (long)b * batchA;
  const u16* Bb = Bt + (long)b * batchB;
  const int row0 = by * BM;
  const int col0 = bx * BN;
  const int tid = threadIdx.x;
  const int lane = tid & 63, wid = tid >> 6;
  const int wr = wid >> 1, wc = wid & 1;             // 2x2 wave grid, 64x64 each
  const int l15 = lane & 15;

  // staging source coords: lane l -> LDS linear byte l*16 within its 16-row issue
  // logical 16B k-chunk = phys ^ ((row>>1)&3); row-in-issue = lane>>2, phys = lane&3
  const int srow = lane >> 2;
  const int scol = ((lane & 3) ^ ((lane >> 3) & 3)) * 8;
  const u16* pA0 = Ab + (long)(row0 + wid * 32 + srow) * K + scol;
  const u16* pA1 = pA0 + 16 * (long)K;
  const u16* pB0 = Bb + (long)(col0 + wid * 32 + srow) * K + scol;
  const u16* pB1 = pB0 + 16 * (long)K;
  u16* lA0 = &As[wid * 1024];  u16* lA1 = lA0 + 512;
  u16* lB0 = &Bs[wid * 1024];  u16* lB1 = lB0 + 512;

  // fragment read offsets (elements): row*32 + (g ^ ((l15>>1)&3))*8
  const int g = lane >> 4;
  const int coff = (g ^ ((l15 >> 1) & 3)) * 8;
  const int abase = (wr * 64 + l15) * 32 + coff;
  const int bbase = (wc * 64 + l15) * 32 + coff;

  f32x4 acc[4][4] = {};

  for (int k0 = 0; k0 < K; k0 += BKK) {
    gload16(pA0 + k0, lA0);
    gload16(pB0 + k0, lB0);
    gload16(pA1 + k0, lA1);
    gload16(pB1 + k0, lB1);
    __syncthreads();            // drains vmcnt -> LDS tiles ready
    s16x8 af[4], bfv[4];
#pragma unroll
    for (int m = 0; m < 4; ++m)
      af[m] = *(const s16x8*)(&As[abase + m * 16 * 32]);
#pragma unroll
    for (int n = 0; n < 4; ++n)
      bfv[n] = *(const s16x8*)(&Bs[bbase + n * 16 * 32]);
#pragma unroll
    for (int m = 0; m < 4; ++m)
#pragma unroll
      for (int n = 0; n < 4; ++n)
        acc[m][n] = __builtin_amdgcn_mfma_f32_16x16x32_bf16(af[m], bfv[n], acc[m][n], 0, 0, 0);
    __syncthreads();            // all reads done before next stage overwrites
  }

  // epilogue: C/D layout col=lane&15, row=(lane>>4)*4+reg  [measured m89/m91]
  const long cb = (long)b * batchC;
#pragma unroll
  for (int m = 0; m < 4; ++m) {
    int rbase = row0 + wr * 64 + m * 16 + (lane >> 4) * 4;
#pragma unroll
    for (int n = 0; n < 4; ++n) {
      int col = col0 + wc * 64 + n * 16 + l15;
#pragma unroll
      for (int rr = 0; rr < 4; ++rr) {
        long cidx = cb + (long)(rbase + rr) * N + col;
        float v = acc[m][n][rr];
        if (EPI == EPI_BF16_BIAS) {
          ((u16*)Cout)[cidx] = f2bf(v + bias[col]);
        } else if (EPI == EPI_F32_SCALE) {
          ((float*)Cout)[cidx] = v * scale;
        } else if (EPI == EPI_F32) {
          ((float*)Cout)[cidx] = v;
        } else if (EPI == EPI_RELU_BF16_BIAS) {
          ((u16*)Cout)[cidx] = f2bf(fmaxf(v + bias[col], 0.0f));
        } else { // EPI_F32_BIAS_RESID
          ((float*)Cout)[cidx] = v + bias[col] + resid[cidx];
        }
      }
    }
  }
}

// ---------- per-row top-k threshold (radix select) + sparse softmax ----------
// Reference: sparse = where(score >= kth_largest, score, 0); softmax over ALL
// entries (dropped ones contribute exp(0 - m)). One block per row, S=2048.
__global__ __launch_bounds__(256)
void topk_softmax(const float* __restrict__ scores, u16* __restrict__ P, int topk) {
  const long rowoff = (long)blockIdx.x * 2048;
  const int tid = threadIdx.x, lane = tid & 63, wid = tid >> 6;
  __shared__ float sred[4];
  __shared__ int ired[4];

  float v[8]; uint32_t kv[8];
#pragma unroll
  for (int j = 0; j < 8; ++j) {
    float f = scores[rowoff + j * 256 + tid];
    v[j] = f;
    union { float f; uint32_t u; } c; c.f = f;
    kv[j] = (c.u & 0x80000000u) ? ~c.u : (c.u | 0x80000000u);  // monotonic key
  }
  // row max
  float m = v[0];
#pragma unroll
  for (int j = 1; j < 8; ++j) m = fmaxf(m, v[j]);
  m = wave_max_f(m);
  if (lane == 0) sred[wid] = m;
  __syncthreads();
  m = fmaxf(fmaxf(sred[0], sred[1]), fmaxf(sred[2], sred[3]));
  __syncthreads();

  // bitwise radix select: cur -> topk-th largest key
  uint32_t cur = 0;
  for (int bit = 31; bit >= 0; --bit) {
    uint32_t cand = cur | (1u << bit);
    int c = 0;
#pragma unroll
    for (int j = 0; j < 8; ++j) c += (kv[j] >= cand);
    c = wave_sum_i(c);
    if (lane == 0) ired[wid] = c;
    __syncthreads();
    int tot = ired[0] + ired[1] + ired[2] + ired[3];
    __syncthreads();
    if (tot >= topk) cur = cand;
  }

  // sparse softmax: dropped -> 0.0; row max of sparse row = max(m, 0)
  float mm = fmaxf(m, 0.0f);
  float p[8], s = 0.0f;
#pragma unroll
  for (int j = 0; j < 8; ++j) {
    float val = (kv[j] >= cur) ? v[j] : 0.0f;
    p[j] = __expf(val - mm);
    s += p[j];
  }
  s = wave_sum_f(s);
  if (lane == 0) sred[wid] = s;
  __syncthreads();
  float inv = 1.0f / (sred[0] + sred[1] + sred[2] + sred[3]);
#pragma unroll
  for (int j = 0; j < 8; ++j) P[rowoff + j * 256 + tid] = f2bf(p[j] * inv);
}

// ---------- fused (a [+ r]) -> LayerNorm -> fp32 out [+ bf16 out] ----------
__global__ __launch_bounds__(256)
void add_ln(const float* __restrict__ a, const float* __restrict__ r,
            const float* __restrict__ gamma, const float* __restrict__ beta,
            float* __restrict__ outf, u16* __restrict__ outb) {
  const long off = (long)blockIdx.x * 1024;
  const int tid = threadIdx.x, lane = tid & 63, wid = tid >> 6;
  __shared__ float sred[4];
  float x[4];
#pragma unroll
  for (int j = 0; j < 4; ++j) {
    int col = j * 256 + tid;
    float t = a[off + col];
    if (r) t += r[off + col];
    x[j] = t;
  }
  float s = x[0] + x[1] + x[2] + x[3];
  s = wave_sum_f(s);
  if (lane == 0) sred[wid] = s;
  __syncthreads();
  float mu = (sred[0] + sred[1] + sred[2] + sred[3]) * (1.0f / 1024.0f);
  __syncthreads();
  float qv = 0.0f;
#pragma unroll
  for (int j = 0; j < 4; ++j) { float d = x[j] - mu; qv += d * d; }
  qv = wave_sum_f(qv);
  if (lane == 0) sred[wid] = qv;
  __syncthreads();
  float var = (sred[0] + sred[1] + sred[2] + sred[3]) * (1.0f / 1024.0f);
  float inv = rsqrtf(var + 1e-6f);
#pragma unroll
  for (int j = 0; j < 4; ++j) {
    int col = j * 256 + tid;
    float o = (x[j] - mu) * inv * gamma[col] + beta[col];
    if (outf) outf[off + col] = o;
    if (outb) outb[off + col] = f2bf(o);
  }
}

// ---------- launch ----------
extern "C" void kernel_launch(void* const* d_in, const int* in_sizes, int n_in,
                              void* d_out, int out_size, void* d_ws, size_t ws_size,
                              hipStream_t stream) {
  const float* x   = (const float*)d_in[0];
  const float* Wq  = (const float*)d_in[1];
  const float* bq  = (const float*)d_in[2];
  const float* Wk  = (const float*)d_in[3];
  const float* bk  = (const float*)d_in[4];
  const float* Wv  = (const float*)d_in[5];
  const float* bv  = (const float*)d_in[6];
  const float* W1  = (const float*)d_in[7];
  const float* b1  = (const float*)d_in[8];
  const float* W2  = (const float*)d_in[9];
  const float* b2  = (const float*)d_in[10];
  const float* g1  = (const float*)d_in[11];
  const float* be1 = (const float*)d_in[12];
  const float* g2  = (const float*)d_in[13];
  const float* be2 = (const float*)d_in[14];

  const int Bz = 4, S = 2048, Dm = 1024, Ff = 4096;
  const int M = Bz * S; // 8192

  char* ws = (char*)d_ws;
  const size_t MBy = 1024u * 1024u;
  // slab plan (peak 198 MB), reuse after liveness ends:
  u16*  wqT    = (u16*)(ws + 0 * MBy);     // 2 MB [Dm][Dm]
  u16*  wkT    = (u16*)(ws + 2 * MBy);
  u16*  wvT    = (u16*)(ws + 4 * MBy);
  u16*  w1T    = (u16*)(ws + 6 * MBy);     // 8 MB [Ff][Dm]
  u16*  w2T    = (u16*)(ws + 14 * MBy);    // 8 MB [Dm][Ff]
  u16*  xbf    = (u16*)(ws + 22 * MBy);    // 16 MB
  u16*  qbf    = (u16*)(ws + 38 * MBy);    // 16 MB
  u16*  kbf    = (u16*)(ws + 54 * MBy);    // 16 MB
  u16*  vbf    = (u16*)(ws + 70 * MBy);    // 16 MB
  u16*  vT     = (u16*)(ws + 86 * MBy);    // 16 MB [B][Dm][S]
  float* scores= (float*)(ws + 102 * MBy); // 64 MB [B][S][S]
  u16*  P      = (u16*)(ws + 166 * MBy);   // 32 MB
  float* attn  = (float*)(ws + 102 * MBy); // 32 MB (reuse scores; dead after softmax)
  float* out1  = (float*)(ws + 134 * MBy); // 32 MB
  u16*  out1b  = (u16*)(ws + 22 * MBy);    // 16 MB (reuse xbf)
  u16*  hbf    = (u16*)(ws + 38 * MBy);    // 64 MB (reuse q/k/v/vT)
  float* y     = (float*)(ws + 166 * MBy); // 32 MB (reuse P)

  dim3 blk(256);

  // casts
  cast_f32_bf16<<<dim3((unsigned)((long)M * Dm / 1024)), blk, 0, stream>>>(x, xbf);
  transpose_cast_f32_bf16<<<dim3(Dm / 32, Dm / 32), blk, 0, stream>>>(Wq, wqT, Dm, Dm);
  transpose_cast_f32_bf16<<<dim3(Dm / 32, Dm / 32), blk, 0, stream>>>(Wk, wkT, Dm, Dm);
  transpose_cast_f32_bf16<<<dim3(Dm / 32, Dm / 32), blk, 0, stream>>>(Wv, wvT, Dm, Dm);
  transpose_cast_f32_bf16<<<dim3(Ff / 32, Dm / 32), blk, 0, stream>>>(W1, w1T, Dm, Ff);
  transpose_cast_f32_bf16<<<dim3(Dm / 32, Ff / 32), blk, 0, stream>>>(W2, w2T, Ff, Dm);

  // QKV projections: [M][Dm] = xbf @ W^T, +bias, out bf16
  {
    int tx = Dm / BN, ty = M / BM;
    dim3 grd(tx * ty);
    gemm_bt<EPI_BF16_BIAS><<<grd, blk, 0, stream>>>(
        xbf, wqT, bq, nullptr, qbf, M, Dm, Dm, tx, ty, 0, 0, 0, 1.0f);
    gemm_bt<EPI_BF16_BIAS><<<grd, blk, 0, stream>>>(
        xbf, wkT, bk, nullptr, kbf, M, Dm, Dm, tx, ty, 0, 0, 0, 1.0f);
    gemm_bt<EPI_BF16_BIAS><<<grd, blk, 0, stream>>>(
        xbf, wvT, bv, nullptr, vbf, M, Dm, Dm, tx, ty, 0, 0, 0, 1.0f);
  }

  // v -> v^T per batch for PV GEMM
  transpose_bf16<<<dim3(Dm / 32, S / 32, Bz), blk, 0, stream>>>(vbf, vT, S, Dm);

  // scores[b] = q[b] @ k[b]^T / sqrt(Dm)   (k row-major IS the Bt format)
  {
    int tx = S / BN, ty = S / BM;
    gemm_bt<EPI_F32_SCALE><<<dim3(tx * ty * Bz), blk, 0, stream>>>(
        qbf, kbf, nullptr, nullptr, scores, S, S, Dm, tx, ty,
        (long long)S * Dm, (long long)S * Dm, (long long)S * S, 0.03125f);
  }

  // top-k threshold + sparse softmax -> P (bf16)
  topk_softmax<<<dim3(Bz * S), blk, 0, stream>>>(scores, P, S / 2);

  // attn_out[b] = P[b] @ v[b]
  {
    int tx = Dm / BN, ty = S / BM;
    gemm_bt<EPI_F32><<<dim3(tx * ty * Bz), blk, 0, stream>>>(
        P, vT, nullptr, nullptr, attn, S, Dm, S, tx, ty,
        (long long)S * S, (long long)Dm * S, (long long)S * Dm, 1.0f);
  }

  // out1 = LN(x + attn_out) -> fp32 + bf16
  add_ln<<<dim3(M), blk, 0, stream>>>(x, attn, g1, be1, out1, out1b);

  // h = relu(out1 @ W1 + b1) -> bf16
  {
    int tx = Ff / BN, ty = M / BM;
    gemm_bt<EPI_RELU_BF16_BIAS><<<dim3(tx * ty), blk, 0, stream>>>(
        out1b, w1T, b1, nullptr, hbf, M, Ff, Dm, tx, ty, 0, 0, 0, 1.0f);
  }

  // y = h @ W2 + b2 + out1
  {
    int tx = Dm / BN, ty = M / BM;
    gemm_bt<EPI_F32_BIAS_RESID><<<dim3(tx * ty), blk, 0, stream>>>(
        hbf, w2T, b2, out1, y, M, Dm, Ff, tx, ty, 0, 0, 0, 1.0f);
  }

  // out = LN(y)
  add_ln<<<dim3(M), blk, 0, stream>>>(y, nullptr, g2, be2, (float*)d_out, nullptr);
}

// Round 3
// 499.557 us; speedup vs baseline: 1.1423x; 1.0131x over previous
//
#include <hip/hip_runtime.h>
#include <cstdint>

typedef unsigned short u16;
typedef __attribute__((ext_vector_type(8))) short s16x8;   // 8 bf16 (4 VGPR) MFMA A/B frag
typedef __attribute__((ext_vector_type(4))) unsigned short u16x4;
typedef __attribute__((ext_vector_type(4))) float f32x4;   // MFMA C/D frag

// ---------- helpers ----------
__device__ __forceinline__ u16 f2bf(float f) {
  union { float f; uint32_t u; } c; c.f = f;
  uint32_t r = c.u + 0x7FFFu + ((c.u >> 16) & 1u);   // RNE
  return (u16)(r >> 16);
}
__device__ __forceinline__ float wave_sum_f(float v) {
#pragma unroll
  for (int o = 32; o > 0; o >>= 1) v += __shfl_xor(v, o);
  return v;
}
__device__ __forceinline__ float wave_max_f(float v) {
#pragma unroll
  for (int o = 32; o > 0; o >>= 1) v = fmaxf(v, __shfl_xor(v, o));
  return v;
}
__device__ __forceinline__ int wave_sum_i(int v) {
#pragma unroll
  for (int o = 32; o > 0; o >>= 1) v += __shfl_xor(v, o);
  return v;
}
// async global->LDS, 16B per lane, wave-uniform LDS base (+lane*16 implicit)
__device__ __forceinline__ void gload16(const u16* g, u16* l) {
  __builtin_amdgcn_global_load_lds(
      (const __attribute__((address_space(1))) unsigned int*)g,
      (__attribute__((address_space(3))) unsigned int*)l,
      16, 0, 0);
}

// ---------- elementwise cast fp32 -> bf16 ----------
__global__ __launch_bounds__(256)
void cast_f32_bf16(const float* __restrict__ in, u16* __restrict__ out) {
  long i = ((long)blockIdx.x * 256 + threadIdx.x) * 4;
  f32x4 v = *(const f32x4*)(in + i);
  u16x4 o;
#pragma unroll
  for (int j = 0; j < 4; ++j) o[j] = f2bf(v[j]);
  *(u16x4*)(out + i) = o;
}

// ---------- concat 3 bias vectors (1024 each) ----------
__global__ __launch_bounds__(256)
void concat3(const float* __restrict__ a, const float* __restrict__ b,
             const float* __restrict__ c, float* __restrict__ o) {
  int i = blockIdx.x * 256 + threadIdx.x;
  o[i] = i < 1024 ? a[i] : (i < 2048 ? b[i - 1024] : c[i - 2048]);
}

// ---------- cast+transpose fp32 [R][C] -> bf16 [C][R] ----------
__global__ __launch_bounds__(256)
void transpose_cast_f32_bf16(const float* __restrict__ in, u16* __restrict__ out,
                             int R, int C) {
  __shared__ float tile[32][33];
  int r0 = blockIdx.y * 32, c0 = blockIdx.x * 32;
  int tid = threadIdx.x;
  int tr = tid >> 3, tc4 = (tid & 7) * 4;
  f32x4 v = *(const f32x4*)(in + (long)(r0 + tr) * C + c0 + tc4);
#pragma unroll
  for (int j = 0; j < 4; ++j) tile[tr][tc4 + j] = v[j];
  __syncthreads();
  u16x4 o;
#pragma unroll
  for (int j = 0; j < 4; ++j) o[j] = f2bf(tile[tc4 + j][tr]);
  *(u16x4*)(out + (long)(c0 + tr) * R + r0 + tc4) = o;
}

// ---------- strided transpose bf16: in[z][r][c] (row stride in_rs) -> out[z][c][r] ----------
__global__ __launch_bounds__(256)
void transpose_bf16(const u16* __restrict__ in, u16* __restrict__ out,
                    int R, int C, int in_rs, long in_batch, long out_batch) {
  __shared__ u16 tile[32][36];
  const long zin = (long)blockIdx.z * in_batch;
  const long zout = (long)blockIdx.z * out_batch;
  int r0 = blockIdx.y * 32, c0 = blockIdx.x * 32;
  int tid = threadIdx.x;
  int tr = tid >> 3, tc4 = (tid & 7) * 4;
  u16x4 v = *(const u16x4*)(in + zin + (long)(r0 + tr) * in_rs + c0 + tc4);
#pragma unroll
  for (int j = 0; j < 4; ++j) tile[tr][tc4 + j] = v[j];
  __syncthreads();
  u16x4 o;
#pragma unroll
  for (int j = 0; j < 4; ++j) o[j] = tile[tc4 + j][tr];
  *(u16x4*)(out + zout + (long)(c0 + tr) * R + r0 + tc4) = o;
}

// ---------- generic MFMA GEMM: C[M][N] = A[M][K] @ Bt[N][K]^T, batched ----------
// 128x128 tile, BK=32, DOUBLE-BUFFERED global_load_lds width=16 into linear LDS,
// both-sides XOR chunk swizzle (phys16Bchunk = logical ^ ((row>>1)&3)) -> 2-way
// banks = free (m136; SQ_LDS_BANK_CONFLICT measured 0). 2-phase schedule (T3
// minimum recipe): stage t+1 BEFORE computing t, single barrier per K-step.
// 1D grid with bijective XCD swizzle (m204). lda/ldb allow strided slices.
#define BM 128
#define BN 128
#define BKK 32

enum { EPI_BF16_BIAS = 0, EPI_F32_SCALE = 1, EPI_F32 = 2,
       EPI_RELU_BF16_BIAS = 3, EPI_F32_BIAS_RESID = 4 };

template <int EPI>
__global__ __launch_bounds__(256, 2)
void gemm_bt(const u16* __restrict__ A, const u16* __restrict__ Bt,
             const float* __restrict__ bias, const float* __restrict__ resid,
             void* __restrict__ Cout, int M, int N, int K, int lda, int ldb,
             int tx, int ty,
             long long batchA, long long batchB, long long batchC, float scale) {
  __shared__ u16 As[2][BM * BKK];   // 2 x 8 KB, linear (required by global_load_lds)
  __shared__ u16 Bs[2][BN * BKK];

  // bijective XCD swizzle (m204)
  const int nwg = gridDim.x;
  const int orig = blockIdx.x;
  const int q = nwg >> 3, r = nwg & 7;
  const int xcd = orig & 7, idx = orig >> 3;
  const int wg = (xcd < r ? xcd * (q + 1) : r * (q + 1) + (xcd - r) * q) + idx;
  const int bx = wg % tx;
  const int tmp = wg / tx;
  const int by = tmp % ty;
  const int b  = tmp / ty;

  const u16* Ab = A + (long)b * batchA;
  const u16* Bb = Bt + (long)b * batchB;
  const int row0 = by * BM;
  const int col0 = bx * BN;
  const int tid = threadIdx.x;
  const int lane = tid & 63, wid = tid >> 6;
  const int wr = wid >> 1, wc = wid & 1;             // 2x2 wave grid, 64x64 each
  const int l15 = lane & 15;

  // staging source coords: lane l -> LDS linear byte l*16 within its 16-row issue
  // logical 16B k-chunk = phys ^ ((row>>1)&3); row-in-issue = lane>>2, phys = lane&3
  const int srow = lane >> 2;
  const int scol = ((lane & 3) ^ ((lane >> 3) & 3)) * 8;
  const u16* pA0 = Ab + (long)(row0 + wid * 32 + srow) * lda + scol;
  const u16* pA1 = pA0 + 16 * (long)lda;
  const u16* pB0 = Bb + (long)(col0 + wid * 32 + srow) * ldb + scol;
  const u16* pB1 = pB0 + 16 * (long)ldb;

  // fragment read offsets (elements): row*32 + (g ^ ((l15>>1)&3))*8
  const int g = lane >> 4;
  const int coff = (g ^ ((l15 >> 1) & 3)) * 8;
  const int abase = (wr * 64 + l15) * 32 + coff;
  const int bbase = (wc * 64 + l15) * 32 + coff;

  f32x4 acc[4][4] = {};
  const int nt = K / BKK;

  // prologue: stage tile 0 into buf 0
  gload16(pA0, &As[0][wid * 1024]);
  gload16(pA1, &As[0][wid * 1024 + 512]);
  gload16(pB0, &Bs[0][wid * 1024]);
  gload16(pB1, &Bs[0][wid * 1024 + 512]);
  __syncthreads();

  auto compute = [&](int cur) {
    s16x8 af[4], bfv[4];
#pragma unroll
    for (int m = 0; m < 4; ++m)
      af[m] = *(const s16x8*)(&As[cur][abase + m * 512]);
#pragma unroll
    for (int n = 0; n < 4; ++n)
      bfv[n] = *(const s16x8*)(&Bs[cur][bbase + n * 512]);
#pragma unroll
    for (int m = 0; m < 4; ++m)
#pragma unroll
      for (int n = 0; n < 4; ++n)
        acc[m][n] = __builtin_amdgcn_mfma_f32_16x16x32_bf16(af[m], bfv[n], acc[m][n], 0, 0, 0);
  };

  for (int t = 0; t < nt - 1; ++t) {
    const int cur = t & 1;
    const long ko = (long)(t + 1) * BKK;           // issue next tile FIRST
    gload16(pA0 + ko, &As[cur ^ 1][wid * 1024]);
    gload16(pA1 + ko, &As[cur ^ 1][wid * 1024 + 512]);
    gload16(pB0 + ko, &Bs[cur ^ 1][wid * 1024]);
    gload16(pB1 + ko, &Bs[cur ^ 1][wid * 1024 + 512]);
    compute(cur);                                  // MFMA hides the loads
    __syncthreads();                               // drains vmcnt+lgkmcnt once/K-step
  }
  compute((nt - 1) & 1);                           // tail: no stage, no barrier

  // epilogue: C/D layout col=lane&15, row=(lane>>4)*4+reg  [measured m89/m91]
  const long cb = (long)b * batchC;
#pragma unroll
  for (int m = 0; m < 4; ++m) {
    int rbase = row0 + wr * 64 + m * 16 + (lane >> 4) * 4;
#pragma unroll
    for (int n = 0; n < 4; ++n) {
      int col = col0 + wc * 64 + n * 16 + l15;
#pragma unroll
      for (int rr = 0; rr < 4; ++rr) {
        long cidx = cb + (long)(rbase + rr) * N + col;
        float v = acc[m][n][rr];
        if (EPI == EPI_BF16_BIAS) {
          ((u16*)Cout)[cidx] = f2bf(v + bias[col]);
        } else if (EPI == EPI_F32_SCALE) {
          ((float*)Cout)[cidx] = v * scale;
        } else if (EPI == EPI_F32) {
          ((float*)Cout)[cidx] = v;
        } else if (EPI == EPI_RELU_BF16_BIAS) {
          ((u16*)Cout)[cidx] = f2bf(fmaxf(v + bias[col], 0.0f));
        } else { // EPI_F32_BIAS_RESID
          ((float*)Cout)[cidx] = v + bias[col] + resid[cidx];
        }
      }
    }
  }
}

// ---------- per-row top-k threshold (radix select) + sparse softmax ----------
// Reference: sparse = where(score >= kth_largest, score, 0); softmax over ALL
// entries (dropped ones contribute exp(0 - m)). One block per row, S=2048.
__global__ __launch_bounds__(256)
void topk_softmax(const float* __restrict__ scores, u16* __restrict__ P, int topk) {
  const long rowoff = (long)blockIdx.x * 2048;
  const int tid = threadIdx.x, lane = tid & 63, wid = tid >> 6;
  __shared__ float sred[4];
  __shared__ int ired[4];

  float v[8]; uint32_t kv[8];
#pragma unroll
  for (int j = 0; j < 8; ++j) {
    float f = scores[rowoff + j * 256 + tid];
    v[j] = f;
    union { float f; uint32_t u; } c; c.f = f;
    kv[j] = (c.u & 0x80000000u) ? ~c.u : (c.u | 0x80000000u);  // monotonic key
  }
  // row max
  float m = v[0];
#pragma unroll
  for (int j = 1; j < 8; ++j) m = fmaxf(m, v[j]);
  m = wave_max_f(m);
  if (lane == 0) sred[wid] = m;
  __syncthreads();
  m = fmaxf(fmaxf(sred[0], sred[1]), fmaxf(sred[2], sred[3]));
  __syncthreads();

  // bitwise radix select: cur -> topk-th largest key
  uint32_t cur = 0;
  for (int bit = 31; bit >= 0; --bit) {
    uint32_t cand = cur | (1u << bit);
    int c = 0;
#pragma unroll
    for (int j = 0; j < 8; ++j) c += (kv[j] >= cand);
    c = wave_sum_i(c);
    if (lane == 0) ired[wid] = c;
    __syncthreads();
    int tot = ired[0] + ired[1] + ired[2] + ired[3];
    __syncthreads();
    if (tot >= topk) cur = cand;
  }

  // sparse softmax: dropped -> 0.0; row max of sparse row = max(m, 0)
  float mm = fmaxf(m, 0.0f);
  float p[8], s = 0.0f;
#pragma unroll
  for (int j = 0; j < 8; ++j) {
    float val = (kv[j] >= cur) ? v[j] : 0.0f;
    p[j] = __expf(val - mm);
    s += p[j];
  }
  s = wave_sum_f(s);
  if (lane == 0) sred[wid] = s;
  __syncthreads();
  float inv = 1.0f / (sred[0] + sred[1] + sred[2] + sred[3]);
#pragma unroll
  for (int j = 0; j < 8; ++j) P[rowoff + j * 256 + tid] = f2bf(p[j] * inv);
}

// ---------- fused (a [+ r]) -> LayerNorm -> fp32 out [+ bf16 out] ----------
__global__ __launch_bounds__(256)
void add_ln(const float* __restrict__ a, const float* __restrict__ r,
            const float* __restrict__ gamma, const float* __restrict__ beta,
            float* __restrict__ outf, u16* __restrict__ outb) {
  const long off = (long)blockIdx.x * 1024;
  const int tid = threadIdx.x, lane = tid & 63, wid = tid >> 6;
  __shared__ float sred[4];
  float x[4];
#pragma unroll
  for (int j = 0; j < 4; ++j) {
    int col = j * 256 + tid;
    float t = a[off + col];
    if (r) t += r[off + col];
    x[j] = t;
  }
  float s = x[0] + x[1] + x[2] + x[3];
  s = wave_sum_f(s);
  if (lane == 0) sred[wid] = s;
  __syncthreads();
  float mu = (sred[0] + sred[1] + sred[2] + sred[3]) * (1.0f / 1024.0f);
  __syncthreads();
  float qv = 0.0f;
#pragma unroll
  for (int j = 0; j < 4; ++j) { float d = x[j] - mu; qv += d * d; }
  qv = wave_sum_f(qv);
  if (lane == 0) sred[wid] = qv;
  __syncthreads();
  float var = (sred[0] + sred[1] + sred[2] + sred[3]) * (1.0f / 1024.0f);
  float inv = rsqrtf(var + 1e-6f);
#pragma unroll
  for (int j = 0; j < 4; ++j) {
    int col = j * 256 + tid;
    float o = (x[j] - mu) * inv * gamma[col] + beta[col];
    if (outf) outf[off + col] = o;
    if (outb) outb[off + col] = f2bf(o);
  }
}

// ---------- launch ----------
extern "C" void kernel_launch(void* const* d_in, const int* in_sizes, int n_in,
                              void* d_out, int out_size, void* d_ws, size_t ws_size,
                              hipStream_t stream) {
  const float* x   = (const float*)d_in[0];
  const float* Wq  = (const float*)d_in[1];
  const float* bq  = (const float*)d_in[2];
  const float* Wk  = (const float*)d_in[3];
  const float* bk  = (const float*)d_in[4];
  const float* Wv  = (const float*)d_in[5];
  const float* bv  = (const float*)d_in[6];
  const float* W1  = (const float*)d_in[7];
  const float* b1  = (const float*)d_in[8];
  const float* W2  = (const float*)d_in[9];
  const float* b2  = (const float*)d_in[10];
  const float* g1  = (const float*)d_in[11];
  const float* be1 = (const float*)d_in[12];
  const float* g2  = (const float*)d_in[13];
  const float* be2 = (const float*)d_in[14];

  const int Bz = 4, S = 2048, Dm = 1024, Ff = 4096;
  const int M = Bz * S; // 8192
  const int N3 = 3 * Dm; // 3072

  char* ws = (char*)d_ws;
  const size_t MBy = 1024u * 1024u;
  // slab plan (peak 199 MB):
  u16*  wqkvT  = (u16*)(ws + 0 * MBy);     // 6 MB  [3072][1024]
  u16*  w1T    = (u16*)(ws + 6 * MBy);     // 8 MB  [Ff][Dm]
  u16*  w2T    = (u16*)(ws + 14 * MBy);    // 8 MB  [Dm][Ff]
  u16*  xbf    = (u16*)(ws + 23 * MBy);    // 16 MB
  u16*  qkv    = (u16*)(ws + 39 * MBy);    // 48 MB [8192][3072] fused q|k|v
  u16*  vT     = (u16*)(ws + 87 * MBy);    // 16 MB [B][Dm][S]
  float* bqkv  = (float*)(ws + 103 * MBy); // 12 KB (live only during QKV GEMM)
  float* scores= (float*)(ws + 103 * MBy); // 64 MB [B][S][S] (after QKV done)
  u16*  P      = (u16*)(ws + 167 * MBy);   // 32 MB
  float* attn  = (float*)(ws + 103 * MBy); // 32 MB (reuse scores; dead after softmax)
  float* out1  = (float*)(ws + 135 * MBy); // 32 MB
  u16*  out1b  = (u16*)(ws + 23 * MBy);    // 16 MB (reuse xbf)
  u16*  hbf    = (u16*)(ws + 39 * MBy);    // 64 MB (reuse qkv+vT)
  float* y     = (float*)(ws + 167 * MBy); // 32 MB (reuse P)

  dim3 blk(256);

  // casts / weight prep
  cast_f32_bf16<<<dim3((unsigned)((long)M * Dm / 1024)), blk, 0, stream>>>(x, xbf);
  transpose_cast_f32_bf16<<<dim3(Dm / 32, Dm / 32), blk, 0, stream>>>(Wq, wqkvT, Dm, Dm);
  transpose_cast_f32_bf16<<<dim3(Dm / 32, Dm / 32), blk, 0, stream>>>(Wk, wqkvT + 1024 * 1024, Dm, Dm);
  transpose_cast_f32_bf16<<<dim3(Dm / 32, Dm / 32), blk, 0, stream>>>(Wv, wqkvT + 2048 * 1024, Dm, Dm);
  transpose_cast_f32_bf16<<<dim3(Ff / 32, Dm / 32), blk, 0, stream>>>(W1, w1T, Dm, Ff);
  transpose_cast_f32_bf16<<<dim3(Dm / 32, Ff / 32), blk, 0, stream>>>(W2, w2T, Ff, Dm);
  concat3<<<dim3(12), blk, 0, stream>>>(bq, bk, bv, bqkv);

  // fused QKV projection: [M][3072] = xbf @ wqkvT^T + bqkv
  {
    int tx = N3 / BN, ty = M / BM;   // 24 x 64 = 1536 blocks
    gemm_bt<EPI_BF16_BIAS><<<dim3(tx * ty), blk, 0, stream>>>(
        xbf, wqkvT, bqkv, nullptr, qkv, M, N3, Dm, Dm, Dm, tx, ty, 0, 0, 0, 1.0f);
  }

  // v slice -> v^T per batch for PV GEMM
  transpose_bf16<<<dim3(Dm / 32, S / 32, Bz), blk, 0, stream>>>(
      qkv + 2048, vT, S, Dm, N3, (long)S * N3, (long)Dm * S);

  // scores[b] = q[b] @ k[b]^T / sqrt(Dm)
  {
    int tx = S / BN, ty = S / BM;    // 16 x 16 x 4 = 1024 blocks
    gemm_bt<EPI_F32_SCALE><<<dim3(tx * ty * Bz), blk, 0, stream>>>(
        qkv, qkv + 1024, nullptr, nullptr, scores, S, S, Dm, N3, N3, tx, ty,
        (long long)S * N3, (long long)S * N3, (long long)S * S, 0.03125f);
  }

  // top-k threshold + sparse softmax -> P (bf16)
  topk_softmax<<<dim3(Bz * S), blk, 0, stream>>>(scores, P, S / 2);

  // attn_out[b] = P[b] @ v[b]
  {
    int tx = Dm / BN, ty = S / BM;   // 8 x 16 x 4 = 512 blocks
    gemm_bt<EPI_F32><<<dim3(tx * ty * Bz), blk, 0, stream>>>(
        P, vT, nullptr, nullptr, attn, S, Dm, S, S, S, tx, ty,
        (long long)S * S, (long long)Dm * S, (long long)S * Dm, 1.0f);
  }

  // out1 = LN(x + attn_out) -> fp32 + bf16
  add_ln<<<dim3(M), blk, 0, stream>>>(x, attn, g1, be1, out1, out1b);

  // h = relu(out1 @ W1 + b1) -> bf16
  {
    int tx = Ff / BN, ty = M / BM;   // 32 x 64 = 2048 blocks
    gemm_bt<EPI_RELU_BF16_BIAS><<<dim3(tx * ty), blk, 0, stream>>>(
        out1b, w1T, b1, nullptr, hbf, M, Ff, Dm, Dm, Dm, tx, ty, 0, 0, 0, 1.0f);
  }

  // y = h @ W2 + b2 + out1
  {
    int tx = Dm / BN, ty = M / BM;   // 8 x 64 = 512 blocks
    gemm_bt<EPI_F32_BIAS_RESID><<<dim3(tx * ty), blk, 0, stream>>>(
        hbf, w2T, b2, out1, y, M, Dm, Ff, Ff, Ff, tx, ty, 0, 0, 0, 1.0f);
  }

  // out = LN(y)
  add_ln<<<dim3(M), blk, 0, stream>>>(y, nullptr, g2, be2, (float*)d_out, nullptr);
}

// Round 4
// 493.393 us; speedup vs baseline: 1.1566x; 1.0125x over previous
//
#include <hip/hip_runtime.h>
#include <cstdint>

typedef unsigned short u16;
typedef __attribute__((ext_vector_type(8))) short s16x8;   // 8 bf16 (4 VGPR) MFMA A/B frag
typedef __attribute__((ext_vector_type(4))) unsigned short u16x4;
typedef __attribute__((ext_vector_type(4))) float f32x4;   // MFMA C/D frag

// ---------- helpers ----------
__device__ __forceinline__ u16 f2bf(float f) {
  union { float f; uint32_t u; } c; c.f = f;
  uint32_t r = c.u + 0x7FFFu + ((c.u >> 16) & 1u);   // RNE
  return (u16)(r >> 16);
}
__device__ __forceinline__ float wave_sum_f(float v) {
#pragma unroll
  for (int o = 32; o > 0; o >>= 1) v += __shfl_xor(v, o);
  return v;
}
__device__ __forceinline__ float wave_max_f(float v) {
#pragma unroll
  for (int o = 32; o > 0; o >>= 1) v = fmaxf(v, __shfl_xor(v, o));
  return v;
}
__device__ __forceinline__ int wave_sum_i(int v) {
#pragma unroll
  for (int o = 32; o > 0; o >>= 1) v += __shfl_xor(v, o);
  return v;
}
// async global->LDS, 16B per lane, wave-uniform LDS base (+lane*16 implicit)
__device__ __forceinline__ void gload16(const u16* g, u16* l) {
  __builtin_amdgcn_global_load_lds(
      (const __attribute__((address_space(1))) unsigned int*)g,
      (__attribute__((address_space(3))) unsigned int*)l,
      16, 0, 0);
}

// ---------- elementwise cast fp32 -> bf16 ----------
__global__ __launch_bounds__(256)
void cast_f32_bf16(const float* __restrict__ in, u16* __restrict__ out) {
  long i = ((long)blockIdx.x * 256 + threadIdx.x) * 4;
  f32x4 v = *(const f32x4*)(in + i);
  u16x4 o;
#pragma unroll
  for (int j = 0; j < 4; ++j) o[j] = f2bf(v[j]);
  *(u16x4*)(out + i) = o;
}

// ---------- concat 3 bias vectors (1024 each) ----------
__global__ __launch_bounds__(256)
void concat3(const float* __restrict__ a, const float* __restrict__ b,
             const float* __restrict__ c, float* __restrict__ o) {
  int i = blockIdx.x * 256 + threadIdx.x;
  o[i] = i < 1024 ? a[i] : (i < 2048 ? b[i - 1024] : c[i - 2048]);
}

// ---------- cast+transpose fp32 [R][C] -> bf16 [C][R] ----------
__global__ __launch_bounds__(256)
void transpose_cast_f32_bf16(const float* __restrict__ in, u16* __restrict__ out,
                             int R, int C) {
  __shared__ float tile[32][33];
  int r0 = blockIdx.y * 32, c0 = blockIdx.x * 32;
  int tid = threadIdx.x;
  int tr = tid >> 3, tc4 = (tid & 7) * 4;
  f32x4 v = *(const f32x4*)(in + (long)(r0 + tr) * C + c0 + tc4);
#pragma unroll
  for (int j = 0; j < 4; ++j) tile[tr][tc4 + j] = v[j];
  __syncthreads();
  u16x4 o;
#pragma unroll
  for (int j = 0; j < 4; ++j) o[j] = f2bf(tile[tc4 + j][tr]);
  *(u16x4*)(out + (long)(c0 + tr) * R + r0 + tc4) = o;
}

// ---------- strided transpose bf16: in[z][r][c] (row stride in_rs) -> out[z][c][r] ----------
__global__ __launch_bounds__(256)
void transpose_bf16(const u16* __restrict__ in, u16* __restrict__ out,
                    int R, int C, int in_rs, long in_batch, long out_batch) {
  __shared__ u16 tile[32][36];
  const long zin = (long)blockIdx.z * in_batch;
  const long zout = (long)blockIdx.z * out_batch;
  int r0 = blockIdx.y * 32, c0 = blockIdx.x * 32;
  int tid = threadIdx.x;
  int tr = tid >> 3, tc4 = (tid & 7) * 4;
  u16x4 v = *(const u16x4*)(in + zin + (long)(r0 + tr) * in_rs + c0 + tc4);
#pragma unroll
  for (int j = 0; j < 4; ++j) tile[tr][tc4 + j] = v[j];
  __syncthreads();
  u16x4 o;
#pragma unroll
  for (int j = 0; j < 4; ++j) o[j] = tile[tc4 + j][tr];
  *(u16x4*)(out + zout + (long)(c0 + tr) * R + r0 + tc4) = o;
}

// ---------- 8-phase 256-row MFMA GEMM (T2+T3+T4+T5), C = A @ Bt^T ----------
// BM=256, BK=64, 8 waves (2M x 4N), 512 threads, double-buffered LDS.
// Per K-tile: 4 phases, each {ds_read regs || stage 1 half-tile -> s_barrier ->
// setprio(1) MFMA quadrant setprio(0) -> s_barrier}. Counted vmcnt(4) BEFORE
// the K-tile-end barrier (never 0 in steady state). B halves of t+1 go to the
// other buffer (p0,p1); A halves of t+2 go to the CURRENT buffer (p2,p3) --
// safe because all A frags are reg-captured by p1 and pinned with lgkmcnt(0)+
// sched_barrier(0) before p1's end barrier. Involution chunk-swizzle
// (chunk ^= row&7) on pre-swizzled global source + fragment reads: bank-balanced.
#define TBM 256
#define TBK 64

enum { EPI_BF16_BIAS = 0, EPI_F32_SCALE = 1, EPI_F32 = 2,
       EPI_RELU_BF16_BIAS = 3, EPI_F32_BIAS_RESID = 4 };

#define QUAD(MFA)                                                             \
  _Pragma("unroll")                                                           \
  for (int mf = (MFA); mf < (MFA) + 2; ++mf)                                  \
    _Pragma("unroll")                                                         \
    for (int nf = 0; nf < NF; ++nf) {                                         \
      acc[mf][nf] = __builtin_amdgcn_mfma_f32_16x16x32_bf16(                  \
          af[mf][0], bfr[nf][0], acc[mf][nf], 0, 0, 0);                       \
      acc[mf][nf] = __builtin_amdgcn_mfma_f32_16x16x32_bf16(                  \
          af[mf][1], bfr[nf][1], acc[mf][nf], 0, 0, 0);                       \
    }

template <int BN_, int EPI>
__global__ __launch_bounds__(512, 2)
void gemm8p(const u16* __restrict__ A, const u16* __restrict__ Bt,
            const float* __restrict__ bias, const float* __restrict__ resid,
            void* __restrict__ Cout, int M, int N, int K, int lda, int ldb,
            int tx, int ty, long long batchA, long long batchB, long long batchC,
            float scale) {
  constexpr int WN = BN_ / 4;       // per-wave N width (64 or 32)
  constexpr int NF = WN / 16;       // B frags per wave (4 or 2)
  constexpr int NBI = BN_ / 128;    // gload insts per B half-tile (2 or 1)
  __shared__ u16 As[2][TBM * TBK];  // 2 x 32 KB
  __shared__ u16 Bs[2][BN_ * TBK];  // 2 x 32/16 KB

  // bijective XCD swizzle (m204)
  const int nwg = gridDim.x;
  const int orig = blockIdx.x;
  const int q = nwg >> 3, r = nwg & 7;
  const int xcd = orig & 7, idx = orig >> 3;
  const int wg = (xcd < r ? xcd * (q + 1) : r * (q + 1) + (xcd - r) * q) + idx;
  const int bx = wg % tx;
  const int tmp = wg / tx;
  const int by = tmp % ty;
  const int b  = tmp / ty;

  const u16* Ab = A + (long)b * batchA;
  const u16* Bb = Bt + (long)b * batchB;
  const int row0 = by * TBM;
  const int col0 = bx * BN_;
  const int tid = threadIdx.x;
  const int lane = tid & 63, wid = tid >> 6;     // 8 waves
  const int wm = wid >> 2, wn = wid & 3;         // 2 x 4 wave grid
  const int l15 = lane & 15, g = lane >> 4;

  // staging lane coords: LDS dest linear (lane*16B), source pre-swizzled
  const int sr = lane >> 3;                  // row within the wave's 8-row slice
  const int sc = ((lane & 7) ^ sr) * 8;      // logical k-chunk (elems)
  const int wrow = wid * 8 + sr;

  // fragment-read physical chunk offsets: phys = (ks*4+g) ^ (row&7), row&7 = l15&7
  const int c0 = ((0 + g) ^ (l15 & 7)) * 8;
  const int c1 = ((4 + g) ^ (l15 & 7)) * 8;

  auto stageA = [&](int h, int kt, int bf_) {
#pragma unroll
    for (int j = 0; j < 2; ++j)
      gload16(Ab + (size_t)(row0 + h * 128 + j * 64 + wrow) * lda + kt * TBK + sc,
              &As[bf_][(h * 128 + j * 64 + wid * 8) * TBK]);
  };
  auto stageB = [&](int h, int kt, int bf_) {
#pragma unroll
    for (int j = 0; j < NBI; ++j)
      gload16(Bb + (size_t)(col0 + h * (BN_ / 2) + j * 64 + wrow) * ldb + kt * TBK + sc,
              &Bs[bf_][(h * (BN_ / 2) + j * 64 + wid * 8) * TBK]);
  };

  s16x8 af[8][2];
  s16x8 bfr[NF][2];
  f32x4 acc[8][NF] = {};
  const int nt = K / TBK;

  // prologue: Ah0(0) Ah1(0) Bh0(0) Bh1(0) Ah0(1) Ah1(1); wait all but Ah(1)
  stageA(0, 0, 0); stageA(1, 0, 0);
  stageB(0, 0, 0); stageB(1, 0, 0);
  if (nt > 1) {
    stageA(0, 1, 1); stageA(1, 1, 1);
    asm volatile("s_waitcnt vmcnt(4)" ::: "memory");
  } else {
    asm volatile("s_waitcnt vmcnt(0)" ::: "memory");
  }
  __builtin_amdgcn_s_barrier();

  for (int t = 0; t < nt; ++t) {
    const int cur = t & 1;
    const u16* Asc = &As[cur][0];
    const u16* Bsc = &Bs[cur][0];

    // ---- phase 0: read all B + A pairs 0,1 ; stage Bh0(t+1) -> other buf
#pragma unroll
    for (int nf = 0; nf < NF; ++nf) {
      const int rb = (wn * WN + nf * 16 + l15) * TBK;
      bfr[nf][0] = *(const s16x8*)(Bsc + rb + c0);
      bfr[nf][1] = *(const s16x8*)(Bsc + rb + c1);
    }
#pragma unroll
    for (int mf = 0; mf < 4; ++mf) {
      const int rb = (wm * 128 + mf * 16 + l15) * TBK;
      af[mf][0] = *(const s16x8*)(Asc + rb + c0);
      af[mf][1] = *(const s16x8*)(Asc + rb + c1);
    }
    if (t + 1 < nt) stageB(0, t + 1, cur ^ 1);
    __builtin_amdgcn_s_barrier();
    __builtin_amdgcn_s_setprio(1);
    QUAD(0)
    __builtin_amdgcn_s_setprio(0);
    __builtin_amdgcn_s_barrier();

    // ---- phase 1: read A pairs 2,3 ; stage Bh1(t+1) -> other buf
#pragma unroll
    for (int mf = 4; mf < 8; ++mf) {
      const int rb = (wm * 128 + mf * 16 + l15) * TBK;
      af[mf][0] = *(const s16x8*)(Asc + rb + c0);
      af[mf][1] = *(const s16x8*)(Asc + rb + c1);
    }
    if (t + 1 < nt) stageB(1, t + 1, cur ^ 1);
    __builtin_amdgcn_s_barrier();
    __builtin_amdgcn_s_setprio(1);
    QUAD(2)
    __builtin_amdgcn_s_setprio(0);
    // pin: ALL A frags of buf[cur] captured before anyone enters phase 2
    asm volatile("s_waitcnt lgkmcnt(0)" ::: "memory");
    __builtin_amdgcn_sched_barrier(0);
    __builtin_amdgcn_s_barrier();

    // ---- phase 2: stage Ah0(t+2) -> CURRENT buf (A region reg-captured)
    if (t + 2 < nt) stageA(0, t + 2, cur);
    __builtin_amdgcn_s_barrier();
    __builtin_amdgcn_s_setprio(1);
    QUAD(4)
    __builtin_amdgcn_s_setprio(0);
    __builtin_amdgcn_s_barrier();

    // ---- phase 3: stage Ah1(t+2) -> CURRENT buf; counted vmcnt BEFORE barrier
    if (t + 2 < nt) stageA(1, t + 2, cur);
    __builtin_amdgcn_s_barrier();
    __builtin_amdgcn_s_setprio(1);
    QUAD(6)
    __builtin_amdgcn_s_setprio(0);
    if (t + 1 < nt) {
      if (t + 2 < nt) asm volatile("s_waitcnt vmcnt(4)" ::: "memory");
      else            asm volatile("s_waitcnt vmcnt(0)" ::: "memory");
    }
    __builtin_amdgcn_s_barrier();
  }

  // epilogue: C/D layout col=lane&15, row=(lane>>4)*4+reg  [measured m89/m91]
  const long cb = (long)b * batchC;
#pragma unroll
  for (int mf = 0; mf < 8; ++mf) {
    const int rbase = row0 + wm * 128 + mf * 16 + g * 4;
#pragma unroll
    for (int nf = 0; nf < NF; ++nf) {
      const int col = col0 + wn * WN + nf * 16 + l15;
#pragma unroll
      for (int rr = 0; rr < 4; ++rr) {
        const long cidx = cb + (long)(rbase + rr) * N + col;
        float v = acc[mf][nf][rr];
        if (EPI == EPI_BF16_BIAS) {
          ((u16*)Cout)[cidx] = f2bf(v + bias[col]);
        } else if (EPI == EPI_F32_SCALE) {
          ((float*)Cout)[cidx] = v * scale;
        } else if (EPI == EPI_F32) {
          ((float*)Cout)[cidx] = v;
        } else if (EPI == EPI_RELU_BF16_BIAS) {
          ((u16*)Cout)[cidx] = f2bf(fmaxf(v + bias[col], 0.0f));
        } else { // EPI_F32_BIAS_RESID
          ((float*)Cout)[cidx] = v + bias[col] + resid[cidx];
        }
      }
    }
  }
}

// ---------- per-row top-k threshold (radix select) + sparse softmax ----------
__global__ __launch_bounds__(256)
void topk_softmax(const float* __restrict__ scores, u16* __restrict__ P, int topk) {
  const long rowoff = (long)blockIdx.x * 2048;
  const int tid = threadIdx.x, lane = tid & 63, wid = tid >> 6;
  __shared__ float sred[4];
  __shared__ int ired[4];

  float v[8]; uint32_t kv[8];
#pragma unroll
  for (int j = 0; j < 8; ++j) {
    float f = scores[rowoff + j * 256 + tid];
    v[j] = f;
    union { float f; uint32_t u; } c; c.f = f;
    kv[j] = (c.u & 0x80000000u) ? ~c.u : (c.u | 0x80000000u);  // monotonic key
  }
  float m = v[0];
#pragma unroll
  for (int j = 1; j < 8; ++j) m = fmaxf(m, v[j]);
  m = wave_max_f(m);
  if (lane == 0) sred[wid] = m;
  __syncthreads();
  m = fmaxf(fmaxf(sred[0], sred[1]), fmaxf(sred[2], sred[3]));
  __syncthreads();

  uint32_t cur = 0;
  for (int bit = 31; bit >= 0; --bit) {
    uint32_t cand = cur | (1u << bit);
    int c = 0;
#pragma unroll
    for (int j = 0; j < 8; ++j) c += (kv[j] >= cand);
    c = wave_sum_i(c);
    if (lane == 0) ired[wid] = c;
    __syncthreads();
    int tot = ired[0] + ired[1] + ired[2] + ired[3];
    __syncthreads();
    if (tot >= topk) cur = cand;
  }

  float mm = fmaxf(m, 0.0f);
  float p[8], s = 0.0f;
#pragma unroll
  for (int j = 0; j < 8; ++j) {
    float val = (kv[j] >= cur) ? v[j] : 0.0f;
    p[j] = __expf(val - mm);
    s += p[j];
  }
  s = wave_sum_f(s);
  if (lane == 0) sred[wid] = s;
  __syncthreads();
  float inv = 1.0f / (sred[0] + sred[1] + sred[2] + sred[3]);
#pragma unroll
  for (int j = 0; j < 8; ++j) P[rowoff + j * 256 + tid] = f2bf(p[j] * inv);
}

// ---------- fused (a [+ r]) -> LayerNorm -> fp32 out [+ bf16 out] ----------
__global__ __launch_bounds__(256)
void add_ln(const float* __restrict__ a, const float* __restrict__ r,
            const float* __restrict__ gamma, const float* __restrict__ beta,
            float* __restrict__ outf, u16* __restrict__ outb) {
  const long off = (long)blockIdx.x * 1024;
  const int tid = threadIdx.x, lane = tid & 63, wid = tid >> 6;
  __shared__ float sred[4];
  float x[4];
#pragma unroll
  for (int j = 0; j < 4; ++j) {
    int col = j * 256 + tid;
    float t = a[off + col];
    if (r) t += r[off + col];
    x[j] = t;
  }
  float s = x[0] + x[1] + x[2] + x[3];
  s = wave_sum_f(s);
  if (lane == 0) sred[wid] = s;
  __syncthreads();
  float mu = (sred[0] + sred[1] + sred[2] + sred[3]) * (1.0f / 1024.0f);
  __syncthreads();
  float qv = 0.0f;
#pragma unroll
  for (int j = 0; j < 4; ++j) { float d = x[j] - mu; qv += d * d; }
  qv = wave_sum_f(qv);
  if (lane == 0) sred[wid] = qv;
  __syncthreads();
  float var = (sred[0] + sred[1] + sred[2] + sred[3]) * (1.0f / 1024.0f);
  float inv = rsqrtf(var + 1e-6f);
#pragma unroll
  for (int j = 0; j < 4; ++j) {
    int col = j * 256 + tid;
    float o = (x[j] - mu) * inv * gamma[col] + beta[col];
    if (outf) outf[off + col] = o;
    if (outb) outb[off + col] = f2bf(o);
  }
}

// ---------- launch ----------
extern "C" void kernel_launch(void* const* d_in, const int* in_sizes, int n_in,
                              void* d_out, int out_size, void* d_ws, size_t ws_size,
                              hipStream_t stream) {
  const float* x   = (const float*)d_in[0];
  const float* Wq  = (const float*)d_in[1];
  const float* bq  = (const float*)d_in[2];
  const float* Wk  = (const float*)d_in[3];
  const float* bk  = (const float*)d_in[4];
  const float* Wv  = (const float*)d_in[5];
  const float* bv  = (const float*)d_in[6];
  const float* W1  = (const float*)d_in[7];
  const float* b1  = (const float*)d_in[8];
  const float* W2  = (const float*)d_in[9];
  const float* b2  = (const float*)d_in[10];
  const float* g1  = (const float*)d_in[11];
  const float* be1 = (const float*)d_in[12];
  const float* g2  = (const float*)d_in[13];
  const float* be2 = (const float*)d_in[14];

  const int Bz = 4, S = 2048, Dm = 1024, Ff = 4096;
  const int M = Bz * S; // 8192
  const int N3 = 3 * Dm; // 3072

  char* ws = (char*)d_ws;
  const size_t MBy = 1024u * 1024u;
  u16*  wqkvT  = (u16*)(ws + 0 * MBy);     // 6 MB  [3072][1024]
  u16*  w1T    = (u16*)(ws + 6 * MBy);     // 8 MB  [Ff][Dm]
  u16*  w2T    = (u16*)(ws + 14 * MBy);    // 8 MB  [Dm][Ff]
  u16*  xbf    = (u16*)(ws + 23 * MBy);    // 16 MB
  u16*  qkv    = (u16*)(ws + 39 * MBy);    // 48 MB [8192][3072] fused q|k|v
  u16*  vT     = (u16*)(ws + 87 * MBy);    // 16 MB [B][Dm][S]
  float* bqkv  = (float*)(ws + 103 * MBy); // 12 KB (live only during QKV GEMM)
  float* scores= (float*)(ws + 103 * MBy); // 64 MB [B][S][S] (after QKV done)
  u16*  P      = (u16*)(ws + 167 * MBy);   // 32 MB
  float* attn  = (float*)(ws + 103 * MBy); // 32 MB (reuse scores)
  float* out1  = (float*)(ws + 135 * MBy); // 32 MB
  u16*  out1b  = (u16*)(ws + 23 * MBy);    // 16 MB (reuse xbf)
  u16*  hbf    = (u16*)(ws + 39 * MBy);    // 64 MB (reuse qkv+vT)
  float* y     = (float*)(ws + 167 * MBy); // 32 MB (reuse P)

  dim3 blk(256);
  dim3 blk8(512);

  // casts / weight prep
  cast_f32_bf16<<<dim3((unsigned)((long)M * Dm / 1024)), blk, 0, stream>>>(x, xbf);
  transpose_cast_f32_bf16<<<dim3(Dm / 32, Dm / 32), blk, 0, stream>>>(Wq, wqkvT, Dm, Dm);
  transpose_cast_f32_bf16<<<dim3(Dm / 32, Dm / 32), blk, 0, stream>>>(Wk, wqkvT + 1024 * 1024, Dm, Dm);
  transpose_cast_f32_bf16<<<dim3(Dm / 32, Dm / 32), blk, 0, stream>>>(Wv, wqkvT + 2048 * 1024, Dm, Dm);
  transpose_cast_f32_bf16<<<dim3(Ff / 32, Dm / 32), blk, 0, stream>>>(W1, w1T, Dm, Ff);
  transpose_cast_f32_bf16<<<dim3(Dm / 32, Ff / 32), blk, 0, stream>>>(W2, w2T, Ff, Dm);
  concat3<<<dim3(12), blk, 0, stream>>>(bq, bk, bv, bqkv);

  // fused QKV projection: [M][3072] = xbf @ wqkvT^T + bqkv   (BN=128: 24x32=768 blocks)
  gemm8p<128, EPI_BF16_BIAS><<<dim3(24 * 32), blk8, 0, stream>>>(
      xbf, wqkvT, bqkv, nullptr, qkv, M, N3, Dm, Dm, Dm, 24, 32, 0, 0, 0, 1.0f);

  // v slice -> v^T per batch for PV GEMM
  transpose_bf16<<<dim3(Dm / 32, S / 32, Bz), blk, 0, stream>>>(
      qkv + 2048, vT, S, Dm, N3, (long)S * N3, (long)Dm * S);

  // scores[b] = q[b] @ k[b]^T / sqrt(Dm)   (BN=256: 8x8x4=256 blocks)
  gemm8p<256, EPI_F32_SCALE><<<dim3(8 * 8 * Bz), blk8, 0, stream>>>(
      qkv, qkv + 1024, nullptr, nullptr, scores, S, S, Dm, N3, N3, 8, 8,
      (long long)S * N3, (long long)S * N3, (long long)S * S, 0.03125f);

  // top-k threshold + sparse softmax -> P (bf16)
  topk_softmax<<<dim3(Bz * S), blk, 0, stream>>>(scores, P, S / 2);

  // attn_out[b] = P[b] @ v[b]   (BN=128: 8x8x4=256 blocks)
  gemm8p<128, EPI_F32><<<dim3(8 * 8 * Bz), blk8, 0, stream>>>(
      P, vT, nullptr, nullptr, attn, S, Dm, S, S, S, 8, 8,
      (long long)S * S, (long long)Dm * S, (long long)S * Dm, 1.0f);

  // out1 = LN(x + attn_out) -> fp32 + bf16
  add_ln<<<dim3(M), blk, 0, stream>>>(x, attn, g1, be1, out1, out1b);

  // h = relu(out1 @ W1 + b1) -> bf16   (BN=256: 16x32=512 blocks)
  gemm8p<256, EPI_RELU_BF16_BIAS><<<dim3(16 * 32), blk8, 0, stream>>>(
      out1b, w1T, b1, nullptr, hbf, M, Ff, Dm, Dm, Dm, 16, 32, 0, 0, 0, 1.0f);

  // y = h @ W2 + b2 + out1   (BN=128: 8x32=256 blocks)
  gemm8p<128, EPI_F32_BIAS_RESID><<<dim3(8 * 32), blk8, 0, stream>>>(
      hbf, w2T, b2, out1, y, M, Dm, Ff, Ff, Ff, 8, 32, 0, 0, 0, 1.0f);

  // out = LN(y)
  add_ln<<<dim3(M), blk, 0, stream>>>(y, nullptr, g2, be2, (float*)d_out, nullptr);
}

// Round 5
// 452.522 us; speedup vs baseline: 1.2610x; 1.0903x over previous
//
#include <hip/hip_runtime.h>
#include <cstdint>

typedef unsigned short u16;
typedef __attribute__((ext_vector_type(8))) short s16x8;   // 8 bf16 (4 VGPR) MFMA A/B frag
typedef __attribute__((ext_vector_type(4))) unsigned short u16x4;
typedef __attribute__((ext_vector_type(4))) float f32x4;   // MFMA C/D frag

// ---------- helpers ----------
__device__ __forceinline__ u16 f2bf(float f) {
  union { float f; uint32_t u; } c; c.f = f;
  uint32_t r = c.u + 0x7FFFu + ((c.u >> 16) & 1u);   // RNE
  return (u16)(r >> 16);
}
__device__ __forceinline__ float wave_sum_f(float v) {
#pragma unroll
  for (int o = 32; o > 0; o >>= 1) v += __shfl_xor(v, o);
  return v;
}
__device__ __forceinline__ float wave_max_f(float v) {
#pragma unroll
  for (int o = 32; o > 0; o >>= 1) v = fmaxf(v, __shfl_xor(v, o));
  return v;
}
__device__ __forceinline__ int wave_sum_i(int v) {
#pragma unroll
  for (int o = 32; o > 0; o >>= 1) v += __shfl_xor(v, o);
  return v;
}
// async global->LDS, 16B per lane, wave-uniform LDS base (+lane*16 implicit)
__device__ __forceinline__ void gload16(const u16* g, u16* l) {
  __builtin_amdgcn_global_load_lds(
      (const __attribute__((address_space(1))) unsigned int*)g,
      (__attribute__((address_space(3))) unsigned int*)l,
      16, 0, 0);
}

// ---------- elementwise cast fp32 -> bf16 ----------
__global__ __launch_bounds__(256)
void cast_f32_bf16(const float* __restrict__ in, u16* __restrict__ out) {
  long i = ((long)blockIdx.x * 256 + threadIdx.x) * 4;
  f32x4 v = *(const f32x4*)(in + i);
  u16x4 o;
#pragma unroll
  for (int j = 0; j < 4; ++j) o[j] = f2bf(v[j]);
  *(u16x4*)(out + i) = o;
}

// ---------- concat 3 bias vectors (1024 each) ----------
__global__ __launch_bounds__(256)
void concat3(const float* __restrict__ a, const float* __restrict__ b,
             const float* __restrict__ c, float* __restrict__ o) {
  int i = blockIdx.x * 256 + threadIdx.x;
  o[i] = i < 1024 ? a[i] : (i < 2048 ? b[i - 1024] : c[i - 2048]);
}

// ---------- cast+transpose fp32 [R][C] -> bf16 [C][R] ----------
__global__ __launch_bounds__(256)
void transpose_cast_f32_bf16(const float* __restrict__ in, u16* __restrict__ out,
                             int R, int C) {
  __shared__ float tile[32][33];
  int r0 = blockIdx.y * 32, c0 = blockIdx.x * 32;
  int tid = threadIdx.x;
  int tr = tid >> 3, tc4 = (tid & 7) * 4;
  f32x4 v = *(const f32x4*)(in + (long)(r0 + tr) * C + c0 + tc4);
#pragma unroll
  for (int j = 0; j < 4; ++j) tile[tr][tc4 + j] = v[j];
  __syncthreads();
  u16x4 o;
#pragma unroll
  for (int j = 0; j < 4; ++j) o[j] = f2bf(tile[tc4 + j][tr]);
  *(u16x4*)(out + (long)(c0 + tr) * R + r0 + tc4) = o;
}

// ---------- strided transpose bf16: in[z][r][c] (row stride in_rs) -> out[z][c][r] ----------
__global__ __launch_bounds__(256)
void transpose_bf16(const u16* __restrict__ in, u16* __restrict__ out,
                    int R, int C, int in_rs, long in_batch, long out_batch) {
  __shared__ u16 tile[32][36];
  const long zin = (long)blockIdx.z * in_batch;
  const long zout = (long)blockIdx.z * out_batch;
  int r0 = blockIdx.y * 32, c0 = blockIdx.x * 32;
  int tid = threadIdx.x;
  int tr = tid >> 3, tc4 = (tid & 7) * 4;
  u16x4 v = *(const u16x4*)(in + zin + (long)(r0 + tr) * in_rs + c0 + tc4);
#pragma unroll
  for (int j = 0; j < 4; ++j) tile[tr][tc4 + j] = v[j];
  __syncthreads();
  u16x4 o;
#pragma unroll
  for (int j = 0; j < 4; ++j) o[j] = tile[tc4 + j][tr];
  *(u16x4*)(out + zout + (long)(c0 + tr) * R + r0 + tc4) = o;
}

// ---------- 8-wave 256-row MFMA GEMM, C = A @ Bt^T ----------
// BM=256, BK=64, 512 threads, double-buffered LDS, counted vmcnt (never 0 in
// steady state), setprio around MFMA clusters, involution chunk-swizzle
// (chunk ^= row&7) on pre-swizzled global source + fragment reads (measured
// 0 bank conflicts). Two geometries:
//   BN=256: waves 2M x 4N (per-wave 128x64, MF=8), 4 phases x 16 MFMA (m201).
//   BN=128: waves 4M x 2N (per-wave 64x64,  MF=4), 2 phases x 16 MFMA
//           (square tile halves LDS-read bytes/FLOP vs old 128x32 geometry).
#define TBM 256
#define TBK 64

enum { EPI_BF16_BIAS = 0, EPI_F32_SCALE = 1, EPI_F32 = 2,
       EPI_RELU_BF16_BIAS = 3, EPI_F32_BIAS_RESID = 4 };

#define QUAD(MFA)                                                             \
  _Pragma("unroll")                                                           \
  for (int mf = (MFA); mf < (MFA) + 2; ++mf)                                  \
    _Pragma("unroll")                                                         \
    for (int nf = 0; nf < 4; ++nf) {                                          \
      acc[mf][nf] = __builtin_amdgcn_mfma_f32_16x16x32_bf16(                  \
          af[mf][0], bfr[nf][0], acc[mf][nf], 0, 0, 0);                       \
      acc[mf][nf] = __builtin_amdgcn_mfma_f32_16x16x32_bf16(                  \
          af[mf][1], bfr[nf][1], acc[mf][nf], 0, 0, 0);                       \
    }

template <int BN_, int EPI>
__global__ __launch_bounds__(512, 2)
void gemm8p(const u16* __restrict__ A, const u16* __restrict__ Bt,
            const float* __restrict__ bias, const float* __restrict__ resid,
            void* __restrict__ Cout, int M, int N, int K, int lda, int ldb,
            int tx, int ty, long long batchA, long long batchB, long long batchC,
            float scale) {
  constexpr int MF = (BN_ == 256) ? 8 : 4;   // A frags per wave
  constexpr int NBI = BN_ / 128;             // gload insts per B half-tile
  __shared__ u16 As[2][TBM * TBK];  // 2 x 32 KB
  __shared__ u16 Bs[2][BN_ * TBK];  // 2 x 32/16 KB

  // bijective XCD swizzle (m204)
  const int nwg = gridDim.x;
  const int orig = blockIdx.x;
  const int q = nwg >> 3, r = nwg & 7;
  const int xcd = orig & 7, idx = orig >> 3;
  const int wg = (xcd < r ? xcd * (q + 1) : r * (q + 1) + (xcd - r) * q) + idx;
  const int bx = wg % tx;
  const int tmp = wg / tx;
  const int by = tmp % ty;
  const int b  = tmp / ty;

  const u16* Ab = A + (long)b * batchA;
  const u16* Bb = Bt + (long)b * batchB;
  const int row0 = by * TBM;
  const int col0 = bx * BN_;
  const int tid = threadIdx.x;
  const int lane = tid & 63, wid = tid >> 6;     // 8 waves
  const int wm = (BN_ == 256) ? (wid >> 2) : (wid >> 1);
  const int wn = (BN_ == 256) ? (wid & 3) : (wid & 1);
  const int rowW = (BN_ == 256) ? wm * 128 : wm * 64;   // wave row base
  const int l15 = lane & 15, g = lane >> 4;

  // staging lane coords: LDS dest linear (lane*16B), source pre-swizzled
  const int sr = lane >> 3;                  // row within the wave's 8-row slice
  const int sc = ((lane & 7) ^ sr) * 8;      // logical k-chunk (elems)
  const int wrow = wid * 8 + sr;

  // fragment-read physical chunk offsets: phys = (ks*4+g) ^ (row&7), row&7 = l15&7
  const int c0 = ((0 + g) ^ (l15 & 7)) * 8;
  const int c1 = ((4 + g) ^ (l15 & 7)) * 8;

  auto stageA = [&](int h, int kt, int bf_) {
#pragma unroll
    for (int j = 0; j < 2; ++j)
      gload16(Ab + (size_t)(row0 + h * 128 + j * 64 + wrow) * lda + kt * TBK + sc,
              &As[bf_][(h * 128 + j * 64 + wid * 8) * TBK]);
  };
  auto stageB = [&](int h, int kt, int bf_) {
#pragma unroll
    for (int j = 0; j < NBI; ++j)
      gload16(Bb + (size_t)(col0 + h * (BN_ / 2) + j * 64 + wrow) * ldb + kt * TBK + sc,
              &Bs[bf_][(h * (BN_ / 2) + j * 64 + wid * 8) * TBK]);
  };

  s16x8 af[MF][2];
  s16x8 bfr[4][2];
  f32x4 acc[MF][4] = {};
  const int nt = K / TBK;

  // prologue: tile0 (A+B) -> buf0, A(1) -> buf1; wait all but A(1)
  stageA(0, 0, 0); stageA(1, 0, 0);
  stageB(0, 0, 0); stageB(1, 0, 0);
  if (nt > 1) {
    stageA(0, 1, 1); stageA(1, 1, 1);
    asm volatile("s_waitcnt vmcnt(4)" ::: "memory");
  } else {
    asm volatile("s_waitcnt vmcnt(0)" ::: "memory");
  }
  __builtin_amdgcn_s_barrier();

  for (int t = 0; t < nt; ++t) {
    const int cur = t & 1;
    const u16* Asc = &As[cur][0];
    const u16* Bsc = &Bs[cur][0];

    if constexpr (BN_ == 256) {
      // ---- phase 0: read all B + A pairs 0,1 ; stage Bh0(t+1) -> other buf
#pragma unroll
      for (int nf = 0; nf < 4; ++nf) {
        const int rb = (wn * 64 + nf * 16 + l15) * TBK;
        bfr[nf][0] = *(const s16x8*)(Bsc + rb + c0);
        bfr[nf][1] = *(const s16x8*)(Bsc + rb + c1);
      }
#pragma unroll
      for (int mf = 0; mf < 4; ++mf) {
        const int rb = (rowW + mf * 16 + l15) * TBK;
        af[mf][0] = *(const s16x8*)(Asc + rb + c0);
        af[mf][1] = *(const s16x8*)(Asc + rb + c1);
      }
      if (t + 1 < nt) stageB(0, t + 1, cur ^ 1);
      __builtin_amdgcn_s_barrier();
      __builtin_amdgcn_s_setprio(1);
      QUAD(0)
      __builtin_amdgcn_s_setprio(0);
      __builtin_amdgcn_s_barrier();

      // ---- phase 1: read A pairs 2,3 ; stage Bh1(t+1) -> other buf
#pragma unroll
      for (int mf = 4; mf < 8; ++mf) {
        const int rb = (rowW + mf * 16 + l15) * TBK;
        af[mf][0] = *(const s16x8*)(Asc + rb + c0);
        af[mf][1] = *(const s16x8*)(Asc + rb + c1);
      }
      if (t + 1 < nt) stageB(1, t + 1, cur ^ 1);
      __builtin_amdgcn_s_barrier();
      __builtin_amdgcn_s_setprio(1);
      QUAD(2)
      __builtin_amdgcn_s_setprio(0);
      // pin: ALL A frags of buf[cur] captured before anyone enters phase 2
      asm volatile("s_waitcnt lgkmcnt(0)" ::: "memory");
      __builtin_amdgcn_sched_barrier(0);
      __builtin_amdgcn_s_barrier();

      // ---- phase 2: stage Ah0(t+2) -> CURRENT buf (A region reg-captured)
      if (t + 2 < nt) stageA(0, t + 2, cur);
      __builtin_amdgcn_s_barrier();
      __builtin_amdgcn_s_setprio(1);
      QUAD(4)
      __builtin_amdgcn_s_setprio(0);
      __builtin_amdgcn_s_barrier();

      // ---- phase 3: stage Ah1(t+2) -> CURRENT buf; counted vmcnt BEFORE barrier
      if (t + 2 < nt) stageA(1, t + 2, cur);
      __builtin_amdgcn_s_barrier();
      __builtin_amdgcn_s_setprio(1);
      QUAD(6)
      __builtin_amdgcn_s_setprio(0);
      if (t + 1 < nt) {
        if (t + 2 < nt) asm volatile("s_waitcnt vmcnt(4)" ::: "memory");
        else            asm volatile("s_waitcnt vmcnt(0)" ::: "memory");
      }
      __builtin_amdgcn_s_barrier();
    } else {
      // ================= BN=128: 2 phases x 16 MFMA =================
      // ---- phase A: ALL frag reads; stage B(t+1) -> other buf
#pragma unroll
      for (int nf = 0; nf < 4; ++nf) {
        const int rb = (wn * 64 + nf * 16 + l15) * TBK;
        bfr[nf][0] = *(const s16x8*)(Bsc + rb + c0);
        bfr[nf][1] = *(const s16x8*)(Bsc + rb + c1);
      }
#pragma unroll
      for (int mf = 0; mf < 4; ++mf) {
        const int rb = (rowW + mf * 16 + l15) * TBK;
        af[mf][0] = *(const s16x8*)(Asc + rb + c0);
        af[mf][1] = *(const s16x8*)(Asc + rb + c1);
      }
      if (t + 1 < nt) { stageB(0, t + 1, cur ^ 1); stageB(1, t + 1, cur ^ 1); }
      // pin: all my buf[cur] reads complete, then all-wave rendezvous ->
      // safe for phase B's A(t+2) writes into buf[cur]
      asm volatile("s_waitcnt lgkmcnt(0)" ::: "memory");
      __builtin_amdgcn_sched_barrier(0);
      __builtin_amdgcn_s_barrier();
      __builtin_amdgcn_s_setprio(1);
      QUAD(0)
      __builtin_amdgcn_s_setprio(0);
      // ---- phase B: stage A(t+2) -> CURRENT buf; MFMA half 2
      if (t + 2 < nt) { stageA(0, t + 2, cur); stageA(1, t + 2, cur); }
      __builtin_amdgcn_s_setprio(1);
      QUAD(2)
      __builtin_amdgcn_s_setprio(0);
      if (t + 1 < nt) {
        if (t + 2 < nt) asm volatile("s_waitcnt vmcnt(4)" ::: "memory");
        else            asm volatile("s_waitcnt vmcnt(0)" ::: "memory");
        __builtin_amdgcn_s_barrier();
      }
    }
  }

  // epilogue: C/D layout col=lane&15, row=(lane>>4)*4+reg  [measured m89/m91]
  const long cb = (long)b * batchC;
#pragma unroll
  for (int mf = 0; mf < MF; ++mf) {
    const int rbase = row0 + rowW + mf * 16 + g * 4;
#pragma unroll
    for (int nf = 0; nf < 4; ++nf) {
      const int col = col0 + wn * 64 + nf * 16 + l15;
#pragma unroll
      for (int rr = 0; rr < 4; ++rr) {
        const long cidx = cb + (long)(rbase + rr) * N + col;
        float v = acc[mf][nf][rr];
        if (EPI == EPI_BF16_BIAS) {
          ((u16*)Cout)[cidx] = f2bf(v + bias[col]);
        } else if (EPI == EPI_F32_SCALE) {
          ((float*)Cout)[cidx] = v * scale;
        } else if (EPI == EPI_F32) {
          ((float*)Cout)[cidx] = v;
        } else if (EPI == EPI_RELU_BF16_BIAS) {
          ((u16*)Cout)[cidx] = f2bf(fmaxf(v + bias[col], 0.0f));
        } else { // EPI_F32_BIAS_RESID
          ((float*)Cout)[cidx] = v + bias[col] + resid[cidx];
        }
      }
    }
  }
}

// ---------- per-row top-k threshold (radix select) + sparse softmax ----------
__global__ __launch_bounds__(256)
void topk_softmax(const float* __restrict__ scores, u16* __restrict__ P, int topk) {
  const long rowoff = (long)blockIdx.x * 2048;
  const int tid = threadIdx.x, lane = tid & 63, wid = tid >> 6;
  __shared__ float sred[4];
  __shared__ int ired[4];

  float v[8]; uint32_t kv[8];
#pragma unroll
  for (int j = 0; j < 8; ++j) {
    float f = scores[rowoff + j * 256 + tid];
    v[j] = f;
    union { float f; uint32_t u; } c; c.f = f;
    kv[j] = (c.u & 0x80000000u) ? ~c.u : (c.u | 0x80000000u);  // monotonic key
  }
  float m = v[0];
#pragma unroll
  for (int j = 1; j < 8; ++j) m = fmaxf(m, v[j]);
  m = wave_max_f(m);
  if (lane == 0) sred[wid] = m;
  __syncthreads();
  m = fmaxf(fmaxf(sred[0], sred[1]), fmaxf(sred[2], sred[3]));
  __syncthreads();

  uint32_t cur = 0;
  for (int bit = 31; bit >= 0; --bit) {
    uint32_t cand = cur | (1u << bit);
    int c = 0;
#pragma unroll
    for (int j = 0; j < 8; ++j) c += (kv[j] >= cand);
    c = wave_sum_i(c);
    if (lane == 0) ired[wid] = c;
    __syncthreads();
    int tot = ired[0] + ired[1] + ired[2] + ired[3];
    __syncthreads();
    if (tot >= topk) cur = cand;
  }

  float mm = fmaxf(m, 0.0f);
  float p[8], s = 0.0f;
#pragma unroll
  for (int j = 0; j < 8; ++j) {
    float val = (kv[j] >= cur) ? v[j] : 0.0f;
    p[j] = __expf(val - mm);
    s += p[j];
  }
  s = wave_sum_f(s);
  if (lane == 0) sred[wid] = s;
  __syncthreads();
  float inv = 1.0f / (sred[0] + sred[1] + sred[2] + sred[3]);
#pragma unroll
  for (int j = 0; j < 8; ++j) P[rowoff + j * 256 + tid] = f2bf(p[j] * inv);
}

// ---------- fused (a [+ r]) -> LayerNorm -> fp32 out [+ bf16 out] ----------
__global__ __launch_bounds__(256)
void add_ln(const float* __restrict__ a, const float* __restrict__ r,
            const float* __restrict__ gamma, const float* __restrict__ beta,
            float* __restrict__ outf, u16* __restrict__ outb) {
  const long off = (long)blockIdx.x * 1024;
  const int tid = threadIdx.x, lane = tid & 63, wid = tid >> 6;
  __shared__ float sred[4];
  float x[4];
#pragma unroll
  for (int j = 0; j < 4; ++j) {
    int col = j * 256 + tid;
    float t = a[off + col];
    if (r) t += r[off + col];
    x[j] = t;
  }
  float s = x[0] + x[1] + x[2] + x[3];
  s = wave_sum_f(s);
  if (lane == 0) sred[wid] = s;
  __syncthreads();
  float mu = (sred[0] + sred[1] + sred[2] + sred[3]) * (1.0f / 1024.0f);
  __syncthreads();
  float qv = 0.0f;
#pragma unroll
  for (int j = 0; j < 4; ++j) { float d = x[j] - mu; qv += d * d; }
  qv = wave_sum_f(qv);
  if (lane == 0) sred[wid] = qv;
  __syncthreads();
  float var = (sred[0] + sred[1] + sred[2] + sred[3]) * (1.0f / 1024.0f);
  float inv = rsqrtf(var + 1e-6f);
#pragma unroll
  for (int j = 0; j < 4; ++j) {
    int col = j * 256 + tid;
    float o = (x[j] - mu) * inv * gamma[col] + beta[col];
    if (outf) outf[off + col] = o;
    if (outb) outb[off + col] = f2bf(o);
  }
}

// ---------- launch ----------
extern "C" void kernel_launch(void* const* d_in, const int* in_sizes, int n_in,
                              void* d_out, int out_size, void* d_ws, size_t ws_size,
                              hipStream_t stream) {
  const float* x   = (const float*)d_in[0];
  const float* Wq  = (const float*)d_in[1];
  const float* bq  = (const float*)d_in[2];
  const float* Wk  = (const float*)d_in[3];
  const float* bk  = (const float*)d_in[4];
  const float* Wv  = (const float*)d_in[5];
  const float* bv  = (const float*)d_in[6];
  const float* W1  = (const float*)d_in[7];
  const float* b1  = (const float*)d_in[8];
  const float* W2  = (const float*)d_in[9];
  const float* b2  = (const float*)d_in[10];
  const float* g1  = (const float*)d_in[11];
  const float* be1 = (const float*)d_in[12];
  const float* g2  = (const float*)d_in[13];
  const float* be2 = (const float*)d_in[14];

  const int Bz = 4, S = 2048, Dm = 1024, Ff = 4096;
  const int M = Bz * S; // 8192
  const int N3 = 3 * Dm; // 3072

  char* ws = (char*)d_ws;
  const size_t MBy = 1024u * 1024u;
  u16*  wqkvT  = (u16*)(ws + 0 * MBy);     // 6 MB  [3072][1024]
  u16*  w1T    = (u16*)(ws + 6 * MBy);     // 8 MB  [Ff][Dm]
  u16*  w2T    = (u16*)(ws + 14 * MBy);    // 8 MB  [Dm][Ff]
  u16*  xbf    = (u16*)(ws + 23 * MBy);    // 16 MB
  u16*  qkv    = (u16*)(ws + 39 * MBy);    // 48 MB [8192][3072] fused q|k|v
  u16*  vT     = (u16*)(ws + 87 * MBy);    // 16 MB [B][Dm][S]
  float* bqkv  = (float*)(ws + 103 * MBy); // 12 KB (live only during QKV GEMM)
  float* scores= (float*)(ws + 103 * MBy); // 64 MB [B][S][S] (after QKV done)
  u16*  P      = (u16*)(ws + 167 * MBy);   // 32 MB
  float* attn  = (float*)(ws + 103 * MBy); // 32 MB (reuse scores)
  float* out1  = (float*)(ws + 135 * MBy); // 32 MB
  u16*  out1b  = (u16*)(ws + 23 * MBy);    // 16 MB (reuse xbf)
  u16*  hbf    = (u16*)(ws + 39 * MBy);    // 64 MB (reuse qkv+vT)
  float* y     = (float*)(ws + 167 * MBy); // 32 MB (reuse P)

  dim3 blk(256);
  dim3 blk8(512);

  // casts / weight prep
  cast_f32_bf16<<<dim3((unsigned)((long)M * Dm / 1024)), blk, 0, stream>>>(x, xbf);
  transpose_cast_f32_bf16<<<dim3(Dm / 32, Dm / 32), blk, 0, stream>>>(Wq, wqkvT, Dm, Dm);
  transpose_cast_f32_bf16<<<dim3(Dm / 32, Dm / 32), blk, 0, stream>>>(Wk, wqkvT + 1024 * 1024, Dm, Dm);
  transpose_cast_f32_bf16<<<dim3(Dm / 32, Dm / 32), blk, 0, stream>>>(Wv, wqkvT + 2048 * 1024, Dm, Dm);
  transpose_cast_f32_bf16<<<dim3(Ff / 32, Dm / 32), blk, 0, stream>>>(W1, w1T, Dm, Ff);
  transpose_cast_f32_bf16<<<dim3(Dm / 32, Ff / 32), blk, 0, stream>>>(W2, w2T, Ff, Dm);
  concat3<<<dim3(12), blk, 0, stream>>>(bq, bk, bv, bqkv);

  // fused QKV projection: [M][3072] = xbf @ wqkvT^T + bqkv   (BN=128: 24x32=768 blocks)
  gemm8p<128, EPI_BF16_BIAS><<<dim3(24 * 32), blk8, 0, stream>>>(
      xbf, wqkvT, bqkv, nullptr, qkv, M, N3, Dm, Dm, Dm, 24, 32, 0, 0, 0, 1.0f);

  // v slice -> v^T per batch for PV GEMM
  transpose_bf16<<<dim3(Dm / 32, S / 32, Bz), blk, 0, stream>>>(
      qkv + 2048, vT, S, Dm, N3, (long)S * N3, (long)Dm * S);

  // scores[b] = q[b] @ k[b]^T / sqrt(Dm)   (BN=256: 8x8x4=256 blocks)
  gemm8p<256, EPI_F32_SCALE><<<dim3(8 * 8 * Bz), blk8, 0, stream>>>(
      qkv, qkv + 1024, nullptr, nullptr, scores, S, S, Dm, N3, N3, 8, 8,
      (long long)S * N3, (long long)S * N3, (long long)S * S, 0.03125f);

  // top-k threshold + sparse softmax -> P (bf16)
  topk_softmax<<<dim3(Bz * S), blk, 0, stream>>>(scores, P, S / 2);

  // attn_out[b] = P[b] @ v[b]   (BN=128: 8x8x4=256 blocks)
  gemm8p<128, EPI_F32><<<dim3(8 * 8 * Bz), blk8, 0, stream>>>(
      P, vT, nullptr, nullptr, attn, S, Dm, S, S, S, 8, 8,
      (long long)S * S, (long long)Dm * S, (long long)S * Dm, 1.0f);

  // out1 = LN(x + attn_out) -> fp32 + bf16
  add_ln<<<dim3(M), blk, 0, stream>>>(x, attn, g1, be1, out1, out1b);

  // h = relu(out1 @ W1 + b1) -> bf16   (BN=256: 16x32=512 blocks)
  gemm8p<256, EPI_RELU_BF16_BIAS><<<dim3(16 * 32), blk8, 0, stream>>>(
      out1b, w1T, b1, nullptr, hbf, M, Ff, Dm, Dm, Dm, 16, 32, 0, 0, 0, 1.0f);

  // y = h @ W2 + b2 + out1   (BN=128: 8x32=256 blocks)
  gemm8p<128, EPI_F32_BIAS_RESID><<<dim3(8 * 32), blk8, 0, stream>>>(
      hbf, w2T, b2, out1, y, M, Dm, Ff, Ff, Ff, 8, 32, 0, 0, 0, 1.0f);

  // out = LN(y)
  add_ln<<<dim3(M), blk, 0, stream>>>(y, nullptr, g2, be2, (float*)d_out, nullptr);
}

// Round 6
// 404.709 us; speedup vs baseline: 1.4100x; 1.1181x over previous
//
#include <hip/hip_runtime.h>
#include <cstdint>

typedef unsigned short u16;
typedef __attribute__((ext_vector_type(8))) short s16x8;   // 8 bf16 (4 VGPR) MFMA A/B frag
typedef __attribute__((ext_vector_type(4))) unsigned short u16x4;
typedef __attribute__((ext_vector_type(4))) float f32x4;   // MFMA C/D frag

// ---------- helpers ----------
__device__ __forceinline__ u16 f2bf(float f) {
  union { float f; uint32_t u; } c; c.f = f;
  uint32_t r = c.u + 0x7FFFu + ((c.u >> 16) & 1u);   // RNE
  return (u16)(r >> 16);
}
__device__ __forceinline__ float wave_sum_f(float v) {
#pragma unroll
  for (int o = 32; o > 0; o >>= 1) v += __shfl_xor(v, o);
  return v;
}
__device__ __forceinline__ float wave_max_f(float v) {
#pragma unroll
  for (int o = 32; o > 0; o >>= 1) v = fmaxf(v, __shfl_xor(v, o));
  return v;
}
// async global->LDS, 16B per lane, wave-uniform LDS base (+lane*16 implicit)
__device__ __forceinline__ void gload16(const u16* g, u16* l) {
  __builtin_amdgcn_global_load_lds(
      (const __attribute__((address_space(1))) unsigned int*)g,
      (__attribute__((address_space(3))) unsigned int*)l,
      16, 0, 0);
}

// ---------- elementwise cast fp32 -> bf16 ----------
__global__ __launch_bounds__(256)
void cast_f32_bf16(const float* __restrict__ in, u16* __restrict__ out) {
  long i = ((long)blockIdx.x * 256 + threadIdx.x) * 4;
  f32x4 v = *(const f32x4*)(in + i);
  u16x4 o;
#pragma unroll
  for (int j = 0; j < 4; ++j) o[j] = f2bf(v[j]);
  *(u16x4*)(out + i) = o;
}

// ---------- concat 3 bias vectors (1024 each) ----------
__global__ __launch_bounds__(256)
void concat3(const float* __restrict__ a, const float* __restrict__ b,
             const float* __restrict__ c, float* __restrict__ o) {
  int i = blockIdx.x * 256 + threadIdx.x;
  o[i] = i < 1024 ? a[i] : (i < 2048 ? b[i - 1024] : c[i - 2048]);
}

// ---------- cast+transpose fp32 [R][C] -> bf16 [C][R] ----------
__global__ __launch_bounds__(256)
void transpose_cast_f32_bf16(const float* __restrict__ in, u16* __restrict__ out,
                             int R, int C) {
  __shared__ float tile[32][33];
  int r0 = blockIdx.y * 32, c0 = blockIdx.x * 32;
  int tid = threadIdx.x;
  int tr = tid >> 3, tc4 = (tid & 7) * 4;
  f32x4 v = *(const f32x4*)(in + (long)(r0 + tr) * C + c0 + tc4);
#pragma unroll
  for (int j = 0; j < 4; ++j) tile[tr][tc4 + j] = v[j];
  __syncthreads();
  u16x4 o;
#pragma unroll
  for (int j = 0; j < 4; ++j) o[j] = f2bf(tile[tc4 + j][tr]);
  *(u16x4*)(out + (long)(c0 + tr) * R + r0 + tc4) = o;
}

// ---------- strided transpose bf16: in[z][r][c] (row stride in_rs) -> out[z][c][r] ----------
__global__ __launch_bounds__(256)
void transpose_bf16(const u16* __restrict__ in, u16* __restrict__ out,
                    int R, int C, int in_rs, long in_batch, long out_batch) {
  __shared__ u16 tile[32][36];
  const long zin = (long)blockIdx.z * in_batch;
  const long zout = (long)blockIdx.z * out_batch;
  int r0 = blockIdx.y * 32, c0 = blockIdx.x * 32;
  int tid = threadIdx.x;
  int tr = tid >> 3, tc4 = (tid & 7) * 4;
  u16x4 v = *(const u16x4*)(in + zin + (long)(r0 + tr) * in_rs + c0 + tc4);
#pragma unroll
  for (int j = 0; j < 4; ++j) tile[tr][tc4 + j] = v[j];
  __syncthreads();
  u16x4 o;
#pragma unroll
  for (int j = 0; j < 4; ++j) o[j] = tile[tc4 + j][tr];
  *(u16x4*)(out + zout + (long)(c0 + tr) * R + r0 + tc4) = o;
}

// ---------- 8-wave 256-row MFMA GEMM, C = A @ Bt^T ----------
// BM=256, BK=64, 512 threads, double-buffered LDS, counted vmcnt (never 0 in
// steady state), setprio around MFMA clusters, involution chunk-swizzle
// (chunk ^= row&7) on pre-swizzled global source + fragment reads (measured
// 0 bank conflicts). Two geometries:
//   BN=256: waves 2M x 4N (per-wave 128x64, MF=8), 4 phases x 16 MFMA (m201).
//   BN=128: waves 4M x 2N (per-wave 64x64,  MF=4), 2 phases x 16 MFMA.
#define TBM 256
#define TBK 64

enum { EPI_BF16_BIAS = 0, EPI_F32_SCALE = 1, EPI_F32 = 2,
       EPI_RELU_BF16_BIAS = 3, EPI_F32_BIAS_RESID = 4 };

#define QUAD(MFA)                                                             \
  _Pragma("unroll")                                                           \
  for (int mf = (MFA); mf < (MFA) + 2; ++mf)                                  \
    _Pragma("unroll")                                                         \
    for (int nf = 0; nf < 4; ++nf) {                                          \
      acc[mf][nf] = __builtin_amdgcn_mfma_f32_16x16x32_bf16(                  \
          af[mf][0], bfr[nf][0], acc[mf][nf], 0, 0, 0);                       \
      acc[mf][nf] = __builtin_amdgcn_mfma_f32_16x16x32_bf16(                  \
          af[mf][1], bfr[nf][1], acc[mf][nf], 0, 0, 0);                       \
    }

template <int BN_, int EPI>
__global__ __launch_bounds__(512, 2)
void gemm8p(const u16* __restrict__ A, const u16* __restrict__ Bt,
            const float* __restrict__ bias, const float* __restrict__ resid,
            void* __restrict__ Cout, int M, int N, int K, int lda, int ldb,
            int tx, int ty, long long batchA, long long batchB, long long batchC,
            float scale) {
  constexpr int MF = (BN_ == 256) ? 8 : 4;   // A frags per wave
  constexpr int NBI = BN_ / 128;             // gload insts per B half-tile
  __shared__ u16 As[2][TBM * TBK];  // 2 x 32 KB
  __shared__ u16 Bs[2][BN_ * TBK];  // 2 x 32/16 KB

  // bijective XCD swizzle (m204)
  const int nwg = gridDim.x;
  const int orig = blockIdx.x;
  const int q = nwg >> 3, r = nwg & 7;
  const int xcd = orig & 7, idx = orig >> 3;
  const int wg = (xcd < r ? xcd * (q + 1) : r * (q + 1) + (xcd - r) * q) + idx;
  const int bx = wg % tx;
  const int tmp = wg / tx;
  const int by = tmp % ty;
  const int b  = tmp / ty;

  const u16* Ab = A + (long)b * batchA;
  const u16* Bb = Bt + (long)b * batchB;
  const int row0 = by * TBM;
  const int col0 = bx * BN_;
  const int tid = threadIdx.x;
  const int lane = tid & 63, wid = tid >> 6;     // 8 waves
  const int wm = (BN_ == 256) ? (wid >> 2) : (wid >> 1);
  const int wn = (BN_ == 256) ? (wid & 3) : (wid & 1);
  const int rowW = (BN_ == 256) ? wm * 128 : wm * 64;   // wave row base
  const int l15 = lane & 15, g = lane >> 4;

  // staging lane coords: LDS dest linear (lane*16B), source pre-swizzled
  const int sr = lane >> 3;                  // row within the wave's 8-row slice
  const int sc = ((lane & 7) ^ sr) * 8;      // logical k-chunk (elems)
  const int wrow = wid * 8 + sr;

  // fragment-read physical chunk offsets: phys = (ks*4+g) ^ (row&7), row&7 = l15&7
  const int c0 = ((0 + g) ^ (l15 & 7)) * 8;
  const int c1 = ((4 + g) ^ (l15 & 7)) * 8;

  auto stageA = [&](int h, int kt, int bf_) {
#pragma unroll
    for (int j = 0; j < 2; ++j)
      gload16(Ab + (size_t)(row0 + h * 128 + j * 64 + wrow) * lda + kt * TBK + sc,
              &As[bf_][(h * 128 + j * 64 + wid * 8) * TBK]);
  };
  auto stageB = [&](int h, int kt, int bf_) {
#pragma unroll
    for (int j = 0; j < NBI; ++j)
      gload16(Bb + (size_t)(col0 + h * (BN_ / 2) + j * 64 + wrow) * ldb + kt * TBK + sc,
              &Bs[bf_][(h * (BN_ / 2) + j * 64 + wid * 8) * TBK]);
  };

  s16x8 af[MF][2];
  s16x8 bfr[4][2];
  f32x4 acc[MF][4] = {};
  const int nt = K / TBK;

  // prologue: tile0 (A+B) -> buf0, A(1) -> buf1; wait all but A(1)
  stageA(0, 0, 0); stageA(1, 0, 0);
  stageB(0, 0, 0); stageB(1, 0, 0);
  if (nt > 1) {
    stageA(0, 1, 1); stageA(1, 1, 1);
    asm volatile("s_waitcnt vmcnt(4)" ::: "memory");
  } else {
    asm volatile("s_waitcnt vmcnt(0)" ::: "memory");
  }
  __builtin_amdgcn_s_barrier();

  for (int t = 0; t < nt; ++t) {
    const int cur = t & 1;
    const u16* Asc = &As[cur][0];
    const u16* Bsc = &Bs[cur][0];

    if constexpr (BN_ == 256) {
      // ---- phase 0: read all B + A pairs 0,1 ; stage Bh0(t+1) -> other buf
#pragma unroll
      for (int nf = 0; nf < 4; ++nf) {
        const int rb = (wn * 64 + nf * 16 + l15) * TBK;
        bfr[nf][0] = *(const s16x8*)(Bsc + rb + c0);
        bfr[nf][1] = *(const s16x8*)(Bsc + rb + c1);
      }
#pragma unroll
      for (int mf = 0; mf < 4; ++mf) {
        const int rb = (rowW + mf * 16 + l15) * TBK;
        af[mf][0] = *(const s16x8*)(Asc + rb + c0);
        af[mf][1] = *(const s16x8*)(Asc + rb + c1);
      }
      if (t + 1 < nt) stageB(0, t + 1, cur ^ 1);
      __builtin_amdgcn_s_barrier();
      __builtin_amdgcn_s_setprio(1);
      QUAD(0)
      __builtin_amdgcn_s_setprio(0);
      __builtin_amdgcn_s_barrier();

      // ---- phase 1: read A pairs 2,3 ; stage Bh1(t+1) -> other buf
#pragma unroll
      for (int mf = 4; mf < 8; ++mf) {
        const int rb = (rowW + mf * 16 + l15) * TBK;
        af[mf][0] = *(const s16x8*)(Asc + rb + c0);
        af[mf][1] = *(const s16x8*)(Asc + rb + c1);
      }
      if (t + 1 < nt) stageB(1, t + 1, cur ^ 1);
      __builtin_amdgcn_s_barrier();
      __builtin_amdgcn_s_setprio(1);
      QUAD(2)
      __builtin_amdgcn_s_setprio(0);
      // pin: ALL A frags of buf[cur] captured before anyone enters phase 2
      asm volatile("s_waitcnt lgkmcnt(0)" ::: "memory");
      __builtin_amdgcn_sched_barrier(0);
      __builtin_amdgcn_s_barrier();

      // ---- phase 2: stage Ah0(t+2) -> CURRENT buf (A region reg-captured)
      if (t + 2 < nt) stageA(0, t + 2, cur);
      __builtin_amdgcn_s_barrier();
      __builtin_amdgcn_s_setprio(1);
      QUAD(4)
      __builtin_amdgcn_s_setprio(0);
      __builtin_amdgcn_s_barrier();

      // ---- phase 3: stage Ah1(t+2) -> CURRENT buf; counted vmcnt BEFORE barrier
      if (t + 2 < nt) stageA(1, t + 2, cur);
      __builtin_amdgcn_s_barrier();
      __builtin_amdgcn_s_setprio(1);
      QUAD(6)
      __builtin_amdgcn_s_setprio(0);
      if (t + 1 < nt) {
        if (t + 2 < nt) asm volatile("s_waitcnt vmcnt(4)" ::: "memory");
        else            asm volatile("s_waitcnt vmcnt(0)" ::: "memory");
      }
      __builtin_amdgcn_s_barrier();
    } else {
      // ================= BN=128: 2 phases x 16 MFMA =================
      // ---- phase A: ALL frag reads; stage B(t+1) -> other buf
#pragma unroll
      for (int nf = 0; nf < 4; ++nf) {
        const int rb = (wn * 64 + nf * 16 + l15) * TBK;
        bfr[nf][0] = *(const s16x8*)(Bsc + rb + c0);
        bfr[nf][1] = *(const s16x8*)(Bsc + rb + c1);
      }
#pragma unroll
      for (int mf = 0; mf < 4; ++mf) {
        const int rb = (rowW + mf * 16 + l15) * TBK;
        af[mf][0] = *(const s16x8*)(Asc + rb + c0);
        af[mf][1] = *(const s16x8*)(Asc + rb + c1);
      }
      if (t + 1 < nt) { stageB(0, t + 1, cur ^ 1); stageB(1, t + 1, cur ^ 1); }
      // pin: all my buf[cur] reads complete, then all-wave rendezvous ->
      // safe for phase B's A(t+2) writes into buf[cur]
      asm volatile("s_waitcnt lgkmcnt(0)" ::: "memory");
      __builtin_amdgcn_sched_barrier(0);
      __builtin_amdgcn_s_barrier();
      __builtin_amdgcn_s_setprio(1);
      QUAD(0)
      __builtin_amdgcn_s_setprio(0);
      // ---- phase B: stage A(t+2) -> CURRENT buf; MFMA half 2
      if (t + 2 < nt) { stageA(0, t + 2, cur); stageA(1, t + 2, cur); }
      __builtin_amdgcn_s_setprio(1);
      QUAD(2)
      __builtin_amdgcn_s_setprio(0);
      if (t + 1 < nt) {
        if (t + 2 < nt) asm volatile("s_waitcnt vmcnt(4)" ::: "memory");
        else            asm volatile("s_waitcnt vmcnt(0)" ::: "memory");
        __builtin_amdgcn_s_barrier();
      }
    }
  }

  // epilogue: C/D layout col=lane&15, row=(lane>>4)*4+reg  [measured m89/m91]
  const long cb = (long)b * batchC;
#pragma unroll
  for (int mf = 0; mf < MF; ++mf) {
    const int rbase = row0 + rowW + mf * 16 + g * 4;
#pragma unroll
    for (int nf = 0; nf < 4; ++nf) {
      const int col = col0 + wn * 64 + nf * 16 + l15;
#pragma unroll
      for (int rr = 0; rr < 4; ++rr) {
        const long cidx = cb + (long)(rbase + rr) * N + col;
        float v = acc[mf][nf][rr];
        if (EPI == EPI_BF16_BIAS) {
          ((u16*)Cout)[cidx] = f2bf(v + bias[col]);
        } else if (EPI == EPI_F32_SCALE) {
          ((float*)Cout)[cidx] = v * scale;
        } else if (EPI == EPI_F32) {
          ((float*)Cout)[cidx] = v;
        } else if (EPI == EPI_RELU_BF16_BIAS) {
          ((u16*)Cout)[cidx] = f2bf(fmaxf(v + bias[col], 0.0f));
        } else { // EPI_F32_BIAS_RESID
          ((float*)Cout)[cidx] = v + bias[col] + resid[cidx];
        }
      }
    }
  }
}

// ---------- per-row top-k threshold + sparse softmax: ONE WAVE PER ROW ----------
// 32 values/lane in registers; radix-select counting via ballot+popcount
// (v_cmp -> sgpr pair, s_bcnt on SALU pipe) -- zero barriers, zero LDS.
// Selection semantics identical to block version: maximal cur with
// count(key >= cur) >= topk on monotonic keys; dropped entries -> 0.0 before
// softmax over ALL 2048 entries (row max of sparse row = max(m, 0)).
__global__ __launch_bounds__(256)
void topk_softmax(const float* __restrict__ scores, u16* __restrict__ P, int topk) {
  const int lane = threadIdx.x & 63, wid = threadIdx.x >> 6;
  const long row = (long)blockIdx.x * 4 + wid;
  const long rowoff = row * 2048;

  float v[32]; uint32_t kv[32];
  const float2* src = (const float2*)(scores + rowoff);
#pragma unroll
  for (int j = 0; j < 16; ++j) {           // lane owns cols 2*lane+128j+{0,1}
    float2 f = src[j * 64 + lane];
    v[2 * j] = f.x; v[2 * j + 1] = f.y;
  }
#pragma unroll
  for (int j = 0; j < 32; ++j) {
    union { float f; uint32_t u; } c; c.f = v[j];
    kv[j] = (c.u & 0x80000000u) ? ~c.u : (c.u | 0x80000000u);  // monotonic key
  }
  float m = v[0];
#pragma unroll
  for (int j = 1; j < 32; ++j) m = fmaxf(m, v[j]);
  m = wave_max_f(m);

  uint32_t cur = 0;
  for (int bit = 31; bit >= 0; --bit) {    // rolled: wave-uniform scalar state
    const uint32_t cand = cur | (1u << bit);
    int c = 0;
#pragma unroll
    for (int j = 0; j < 32; ++j)
      c += (int)__popcll(__ballot(kv[j] >= cand));
    if (c >= topk) cur = cand;
  }

  const float mm = fmaxf(m, 0.0f);
  float p[32], s = 0.0f;
#pragma unroll
  for (int j = 0; j < 32; ++j) {
    float val = (kv[j] >= cur) ? v[j] : 0.0f;
    p[j] = __expf(val - mm);
    s += p[j];
  }
  s = wave_sum_f(s);
  const float inv = 1.0f / s;
  uint32_t* dst = (uint32_t*)(P + rowoff);
#pragma unroll
  for (int j = 0; j < 16; ++j) {
    uint32_t w = (uint32_t)f2bf(p[2 * j] * inv) |
                 ((uint32_t)f2bf(p[2 * j + 1] * inv) << 16);
    dst[j * 64 + lane] = w;
  }
}

// ---------- fused (a [+ r]) -> LayerNorm -> fp32 out [+ bf16 out] ----------
__global__ __launch_bounds__(256)
void add_ln(const float* __restrict__ a, const float* __restrict__ r,
            const float* __restrict__ gamma, const float* __restrict__ beta,
            float* __restrict__ outf, u16* __restrict__ outb) {
  const long off = (long)blockIdx.x * 1024;
  const int tid = threadIdx.x, lane = tid & 63, wid = tid >> 6;
  __shared__ float sred[4];
  float x[4];
#pragma unroll
  for (int j = 0; j < 4; ++j) {
    int col = j * 256 + tid;
    float t = a[off + col];
    if (r) t += r[off + col];
    x[j] = t;
  }
  float s = x[0] + x[1] + x[2] + x[3];
  s = wave_sum_f(s);
  if (lane == 0) sred[wid] = s;
  __syncthreads();
  float mu = (sred[0] + sred[1] + sred[2] + sred[3]) * (1.0f / 1024.0f);
  __syncthreads();
  float qv = 0.0f;
#pragma unroll
  for (int j = 0; j < 4; ++j) { float d = x[j] - mu; qv += d * d; }
  qv = wave_sum_f(qv);
  if (lane == 0) sred[wid] = qv;
  __syncthreads();
  float var = (sred[0] + sred[1] + sred[2] + sred[3]) * (1.0f / 1024.0f);
  float inv = rsqrtf(var + 1e-6f);
#pragma unroll
  for (int j = 0; j < 4; ++j) {
    int col = j * 256 + tid;
    float o = (x[j] - mu) * inv * gamma[col] + beta[col];
    if (outf) outf[off + col] = o;
    if (outb) outb[off + col] = f2bf(o);
  }
}

// ---------- launch ----------
extern "C" void kernel_launch(void* const* d_in, const int* in_sizes, int n_in,
                              void* d_out, int out_size, void* d_ws, size_t ws_size,
                              hipStream_t stream) {
  const float* x   = (const float*)d_in[0];
  const float* Wq  = (const float*)d_in[1];
  const float* bq  = (const float*)d_in[2];
  const float* Wk  = (const float*)d_in[3];
  const float* bk  = (const float*)d_in[4];
  const float* Wv  = (const float*)d_in[5];
  const float* bv  = (const float*)d_in[6];
  const float* W1  = (const float*)d_in[7];
  const float* b1  = (const float*)d_in[8];
  const float* W2  = (const float*)d_in[9];
  const float* b2  = (const float*)d_in[10];
  const float* g1  = (const float*)d_in[11];
  const float* be1 = (const float*)d_in[12];
  const float* g2  = (const float*)d_in[13];
  const float* be2 = (const float*)d_in[14];

  const int Bz = 4, S = 2048, Dm = 1024, Ff = 4096;
  const int M = Bz * S; // 8192
  const int N3 = 3 * Dm; // 3072

  char* ws = (char*)d_ws;
  const size_t MBy = 1024u * 1024u;
  u16*  wqkvT  = (u16*)(ws + 0 * MBy);     // 6 MB  [3072][1024]
  u16*  w1T    = (u16*)(ws + 6 * MBy);     // 8 MB  [Ff][Dm]
  u16*  w2T    = (u16*)(ws + 14 * MBy);    // 8 MB  [Dm][Ff]
  u16*  xbf    = (u16*)(ws + 23 * MBy);    // 16 MB
  u16*  qkv    = (u16*)(ws + 39 * MBy);    // 48 MB [8192][3072] fused q|k|v
  u16*  vT     = (u16*)(ws + 87 * MBy);    // 16 MB [B][Dm][S]
  float* bqkv  = (float*)(ws + 103 * MBy); // 12 KB (live only during QKV GEMM)
  float* scores= (float*)(ws + 103 * MBy); // 64 MB [B][S][S] (after QKV done)
  u16*  P      = (u16*)(ws + 167 * MBy);   // 32 MB
  float* attn  = (float*)(ws + 103 * MBy); // 32 MB (reuse scores)
  float* out1  = (float*)(ws + 135 * MBy); // 32 MB
  u16*  out1b  = (u16*)(ws + 23 * MBy);    // 16 MB (reuse xbf)
  u16*  hbf    = (u16*)(ws + 39 * MBy);    // 64 MB (reuse qkv+vT)
  float* y     = (float*)(ws + 167 * MBy); // 32 MB (reuse P)

  dim3 blk(256);
  dim3 blk8(512);

  // casts / weight prep
  cast_f32_bf16<<<dim3((unsigned)((long)M * Dm / 1024)), blk, 0, stream>>>(x, xbf);
  transpose_cast_f32_bf16<<<dim3(Dm / 32, Dm / 32), blk, 0, stream>>>(Wq, wqkvT, Dm, Dm);
  transpose_cast_f32_bf16<<<dim3(Dm / 32, Dm / 32), blk, 0, stream>>>(Wk, wqkvT + 1024 * 1024, Dm, Dm);
  transpose_cast_f32_bf16<<<dim3(Dm / 32, Dm / 32), blk, 0, stream>>>(Wv, wqkvT + 2048 * 1024, Dm, Dm);
  transpose_cast_f32_bf16<<<dim3(Ff / 32, Dm / 32), blk, 0, stream>>>(W1, w1T, Dm, Ff);
  transpose_cast_f32_bf16<<<dim3(Dm / 32, Ff / 32), blk, 0, stream>>>(W2, w2T, Ff, Dm);
  concat3<<<dim3(12), blk, 0, stream>>>(bq, bk, bv, bqkv);

  // fused QKV projection: [M][3072] = xbf @ wqkvT^T + bqkv   (BN=128: 24x32=768 blocks)
  gemm8p<128, EPI_BF16_BIAS><<<dim3(24 * 32), blk8, 0, stream>>>(
      xbf, wqkvT, bqkv, nullptr, qkv, M, N3, Dm, Dm, Dm, 24, 32, 0, 0, 0, 1.0f);

  // v slice -> v^T per batch for PV GEMM
  transpose_bf16<<<dim3(Dm / 32, S / 32, Bz), blk, 0, stream>>>(
      qkv + 2048, vT, S, Dm, N3, (long)S * N3, (long)Dm * S);

  // scores[b] = q[b] @ k[b]^T / sqrt(Dm)   (BN=256: 8x8x4=256 blocks)
  gemm8p<256, EPI_F32_SCALE><<<dim3(8 * 8 * Bz), blk8, 0, stream>>>(
      qkv, qkv + 1024, nullptr, nullptr, scores, S, S, Dm, N3, N3, 8, 8,
      (long long)S * N3, (long long)S * N3, (long long)S * S, 0.03125f);

  // top-k threshold + sparse softmax -> P (bf16): one wave per row
  topk_softmax<<<dim3(Bz * S / 4), blk, 0, stream>>>(scores, P, S / 2);

  // attn_out[b] = P[b] @ v[b]   (BN=128: 8x8x4=256 blocks)
  gemm8p<128, EPI_F32><<<dim3(8 * 8 * Bz), blk8, 0, stream>>>(
      P, vT, nullptr, nullptr, attn, S, Dm, S, S, S, 8, 8,
      (long long)S * S, (long long)Dm * S, (long long)S * Dm, 1.0f);

  // out1 = LN(x + attn_out) -> fp32 + bf16
  add_ln<<<dim3(M), blk, 0, stream>>>(x, attn, g1, be1, out1, out1b);

  // h = relu(out1 @ W1 + b1) -> bf16   (BN=256: 16x32=512 blocks)
  gemm8p<256, EPI_RELU_BF16_BIAS><<<dim3(16 * 32), blk8, 0, stream>>>(
      out1b, w1T, b1, nullptr, hbf, M, Ff, Dm, Dm, Dm, 16, 32, 0, 0, 0, 1.0f);

  // y = h @ W2 + b2 + out1   (BN=128: 8x32=256 blocks)
  gemm8p<128, EPI_F32_BIAS_RESID><<<dim3(8 * 32), blk8, 0, stream>>>(
      hbf, w2T, b2, out1, y, M, Dm, Ff, Ff, Ff, 8, 32, 0, 0, 0, 1.0f);

  // out = LN(y)
  add_ln<<<dim3(M), blk, 0, stream>>>(y, nullptr, g2, be2, (float*)d_out, nullptr);
}